// Round 10
// baseline (7224.501 us; speedup 1.0000x reference)
//
#include <hip/hip_runtime.h>
#include <math.h>

#define BB 256
#define SS 512
#define II 128
#define HH 256

typedef unsigned short ushort_t;
typedef unsigned int uint32;

// d_ws f16 blob element offsets (each a multiple of 8 -> 16B aligned)
#define OFF_WA   0          // 128*384 = 49152   (swizzled, 48 chunks)
#define OFF_BA   49152      // 128
#define OFF_WIH  49280      // 768*128 = 98304   (swizzled, 16 chunks)
#define OFF_BIH  147584     // 768
#define OFF_WHH  148352     // 768*256 = 196608  (swizzled, 32 chunks)
#define OFF_BHH  344960     // 768
#define OFF_WT   345728     // 256
#define OFF_BT   345984     // 1 (padded to 8)
#define OFF_WF   345992     // 256
#define OFF_BF   346248     // 1 (padded to 8)
#define OFF_WAH  346256     // 128*256 = 32768   (Wa h-part only, swizzled, 32 chunks)
#define OFF_WIH8 379024     // Wih in e5m2: 768 rows x 16 chunks x 8 B = 49152 ushort units
#define OFF_GIX  428176     // fp32 [B,S,128] precomputed Wa_x . x_t

#define WHH_LC   12   // chunks of Whh resident in LDS (144 KB)

// ---------- f16 helpers ----------
__device__ __forceinline__ float h2f(ushort_t u) {
    union { ushort_t s[2]; _Float16 h[2]; } v; v.s[0] = u; return (float)v.h[0];
}
__device__ __forceinline__ ushort_t f2h(float f) {
    union { _Float16 h; ushort_t s; } v; v.h = (_Float16)f; return v.s;
}
__device__ __forceinline__ uint32 pack2(float a, float b) {
    union { _Float16 h[2]; uint32 u; } v;
    v.h[0] = (_Float16)a; v.h[1] = (_Float16)b; return v.u;
}
// f16 -> e5m2 byte (top byte of f16, RNE on the 8 dropped mantissa bits).
__device__ __forceinline__ uint32 f2e5m2(float f) {
    uint32 t = (uint32)f2h(f);
    return ((t + 0x7Fu + ((t >> 8) & 1u)) >> 8) & 0xFFu;
}

// packed-f16 dual-MAC: v_dot2_f32_f16 if available, unpack+fma fallback
#if __has_builtin(__builtin_amdgcn_fdot2)
typedef _Float16 v2h __attribute__((ext_vector_type(2)));
__device__ __forceinline__ float dot2u(uint32 w, uint32 v, float acc) {
    return __builtin_amdgcn_fdot2(
        __builtin_bit_cast(v2h, w), __builtin_bit_cast(v2h, v), acc, false);
}
#else
__device__ __forceinline__ float dot2u(uint32 w, uint32 v, float acc) {
    union { uint32 u; _Float16 h[2]; } a, b; a.u = w; b.u = v;
    acc = fmaf((float)a.h[0], (float)b.h[0], acc);
    return fmaf((float)a.h[1], (float)b.h[1], acc);
}
#endif
__device__ __forceinline__ float dot4(uint4 w, uint4 v, float acc) {
    acc = dot2u(w.x, v.x, acc); acc = dot2u(w.y, v.y, acc);
    acc = dot2u(w.z, v.z, acc); return dot2u(w.w, v.w, acc);
}

// e5m2 x4 (one uint32) -> two packed-f16 pairs via byte permute (b<<8 == f16)
#if __has_builtin(__builtin_amdgcn_perm)
__device__ __forceinline__ uint32 e5m2_lo(uint32 w) {    // bytes [0,b0,0,b1]
    return __builtin_amdgcn_perm(0u, w, 0x010c000cu);
}
__device__ __forceinline__ uint32 e5m2_hi(uint32 w) {    // bytes [0,b2,0,b3]
    return __builtin_amdgcn_perm(0u, w, 0x030c020cu);
}
#else
__device__ __forceinline__ uint32 e5m2_lo(uint32 w) {
    return ((w & 0xFFu) << 8) | ((w & 0xFF00u) << 16);
}
__device__ __forceinline__ uint32 e5m2_hi(uint32 w) {
    return ((w >> 16) & 0xFFu) << 8 | (w & 0xFF000000u);
}
#endif
// 8 e5m2 weights (as 2x uint32) . 8 f16 activations (uint4)
__device__ __forceinline__ float dot4f8w(uint32 wlo, uint32 whi, uint4 v, float acc) {
    acc = dot2u(e5m2_lo(wlo), v.x, acc);
    acc = dot2u(e5m2_hi(wlo), v.y, acc);
    acc = dot2u(e5m2_lo(whi), v.z, acc);
    return dot2u(e5m2_hi(whi), v.w, acc);
}

__global__ void cvt_f32_f16(const float* __restrict__ src, ushort_t* __restrict__ dst, int n) {
    int i = blockIdx.x * 256 + threadIdx.x;
    if (i < n) dst[i] = f2h(src[i]);
}

// Swizzled fp32 -> f16: uint4 index = ((row/64)*chunks + c)*64 + (row%64)
__global__ void cvt_swz(const float* __restrict__ src, ushort_t* __restrict__ dst,
                        int rows, int chunks, int srcStride, int colOff) {
    int t = blockIdx.x * 256 + threadIdx.x;
    if (t >= rows * chunks) return;
    int row = t / chunks, c = t % chunks;
    const float* s = src + (size_t)row * srcStride + colOff + c * 8;
    uint4 v;
    v.x = pack2(s[0], s[1]); v.y = pack2(s[2], s[3]);
    v.z = pack2(s[4], s[5]); v.w = pack2(s[6], s[7]);
    ((uint4*)dst)[((size_t)(row >> 6) * chunks + c) * 64 + (row & 63)] = v;
}

// Swizzled fp32 -> e5m2 (8 weights -> uint2), same swizzle in uint2 units.
__global__ void cvt_swz8(const float* __restrict__ src, ushort_t* __restrict__ dst,
                         int rows, int chunks, int srcStride, int colOff) {
    int t = blockIdx.x * 256 + threadIdx.x;
    if (t >= rows * chunks) return;
    int row = t / chunks, c = t % chunks;
    const float* s = src + (size_t)row * srcStride + colOff + c * 8;
    uint2 v;
    v.x = f2e5m2(s[0]) | (f2e5m2(s[1]) << 8) | (f2e5m2(s[2]) << 16) | (f2e5m2(s[3]) << 24);
    v.y = f2e5m2(s[4]) | (f2e5m2(s[5]) << 8) | (f2e5m2(s[6]) << 16) | (f2e5m2(s[7]) << 24);
    ((uint2*)dst)[((size_t)(row >> 6) * chunks + c) * 64 + (row & 63)] = v;
}

// Pre-pass: gix[b,t,i] = dot(Wa_x[i,:], x[b,t,:])  (h-independent, hoisted).
__global__ __launch_bounds__(512, 2) void gix_kernel(
    const float* __restrict__ x, const ushort_t* __restrict__ wsb,
    float* __restrict__ gix)
{
    const int b = blockIdx.x, tid = threadIdx.x;
    const int r4 = tid >> 7, i = tid & 127;
    __shared__ __align__(16) uint32 sxp[4][64];

    uint4 w[16];
    const uint4* wa_g = (const uint4*)(wsb + OFF_WA);
    const size_t gb = (size_t)(i >> 6) * 48 * 64 + (i & 63);
    #pragma unroll
    for (int c = 0; c < 16; ++c) w[c] = wa_g[gb + (size_t)c * 64];

    const float* xb = x + (size_t)b * SS * II;
    float* gout = gix + (size_t)b * SS * II;
    for (int j = 0; j < SS; j += 4) {
        float v = xb[(j + r4) * II + i];
        float vn = __shfl_down(v, 1);
        if (!(i & 1)) sxp[r4][i >> 1] = pack2(v, vn);
        __syncthreads();
        const uint4* sx4 = (const uint4*)sxp[r4];
        float acc = 0.f;
        #pragma unroll
        for (int c = 0; c < 16; ++c) acc = dot4(w[c], sx4[c], acc);
        gout[(j + r4) * II + i] = acc;
        __syncthreads();
    }
}

// ============ main kernel: R4 structure + in-budget stream prefetch ============
// One block (1024 threads) per batch row.
// Waves 0-11 ("gate"): Wih stored e5m2 in wreg[0..7] (32 regs, R7-validated
//   quantization) -> wreg[8..15] freed as an 8-deep ROTATING PREFETCH buffer
//   for the 20 streamed f16 Whh chunks (zero net allocation change: the attn
//   branch's 16-uint4 Wa_h still defines the array's footprint).
//   Schedule: issue 8 loads -> 12 LDS dots while in flight -> consume 4 /
//   reissue 4 (x3) -> drain. 2 accumulator chains. ~8 dots x 3-wave SIMD
//   interleave of cover per group vs R4's ~2-deep.
// Waves 12-15 ("attn"): exactly R4 — Wa_h reg-resident, wave12 softmax,
//   waves 13-14 x prefetch, wave 15 gix prefetch.
__global__ __launch_bounds__(1024, 4) void da_rnn_pf_kernel(
    const float* __restrict__ x,          // fp32 [B,S,I]
    const ushort_t* __restrict__ wsb,     // f16/e5m2 blob in d_ws
    const float* __restrict__ gix,        // fp32 [B,S,I] precomputed
    float* __restrict__ out)              // fp32 [B,1]
{
    const int b    = blockIdx.x;
    const int tid  = threadIdx.x;
    const int lane = tid & 63;
    const int wv   = tid >> 6;
    const bool is_gate = (tid < 3 * HH);

    __shared__ __align__(16) uint32 whh_lds[WHH_LC * 768 * 4];  // 144 KB
    __shared__ __align__(16) uint32 s_xh_p[192];     // packed f16 [x_t(128); h(256)]
    __shared__ __align__(16) uint32 sxw_p[64];       // packed f16 alpha*x_t
    __shared__ __align__(16) float  sred[256];
    __shared__ __align__(16) float  sgi[3 * HH];
    __shared__ __align__(16) float  sgh[3 * HH];
    __shared__ __align__(16) float  sx[2][II];
    __shared__ __align__(16) float  sgix[2][II];
    __shared__ float swave[4];
    __shared__ int   flag_red;
    __shared__ int   flag_xw;

    if (tid == 0) { flag_red = 0; flag_xw = 0; }
    if (tid < II) s_xh_p[64 + tid] = 0u;             // h_0 = 0 (packed)

    // ---- role-overlaid register array (64 VGPRs for BOTH roles) ----
    // gate: [0..7] = Wih e5m2 (2 chunks/uint4), [8..15] = stream prefetch buf
    // attn: [0..15] = Wa_h f16
    uint4 wreg[16];
    const int a   = tid - 3 * HH;
    const int row = a & 127;
    const int s   = a >> 7;
    const uint4* whh_base = (const uint4*)(wsb + OFF_WHH) + (size_t)wv * 32 * 64 + lane;
    float bias_i = 0.f, bias_h = 0.f, ba_a = 0.f, ba_b = 0.f;

    if (is_gate) {
        const uint2* wih8 = (const uint2*)(wsb + OFF_WIH8) + (size_t)wv * 16 * 64 + lane;
        #pragma unroll
        for (int c = 0; c < 8; ++c) {
            uint2 lo = wih8[(2 * c) * 64];
            uint2 hi = wih8[(2 * c + 1) * 64];
            wreg[c].x = lo.x; wreg[c].y = lo.y; wreg[c].z = hi.x; wreg[c].w = hi.y;
        }
        bias_i = h2f(wsb[OFF_BIH + tid]);
        bias_h = h2f(wsb[OFF_BHH + tid]);
        #pragma unroll
        for (int c = 0; c < WHH_LC; ++c)
            ((uint4*)whh_lds)[(wv * WHH_LC + c) * 64 + lane] = whh_base[c * 64];
    } else {
        const uint4* wah_g = (const uint4*)(wsb + OFF_WAH);
        const size_t gbh = ((size_t)(row >> 6) * 32 + s * 16) * 64 + (row & 63);
        #pragma unroll
        for (int i = 0; i < 16; ++i) wreg[i] = wah_g[gbh + (size_t)i * 64];
        ba_a = h2f(wsb[OFF_BA + lane]);
        ba_b = h2f(wsb[OFF_BA + 64 + lane]);
    }

    float h_reg = 0.f, c_reg = 0.f, m_run = -2.0f, l_run = 0.f;
    float wt_j = 0.f, wf_j = 0.f, bt_r = 0.f;
    if (tid < HH) {
        wt_j = h2f(wsb[OFF_WT + tid]);
        wf_j = h2f(wsb[OFF_WF + tid]);
        bt_r = h2f(wsb[OFF_BT]);
    }

    const float* xrow  = x   + (size_t)b * SS * II;
    const float* grow0 = gix + (size_t)b * SS * II;
    if (!is_gate && a >= 64 && a < 192) {            // x_0 load
        const int idx = a - 64;
        sx[0][idx] = xrow[idx];
    }
    if (!is_gate && a >= 192) {                      // gix_0 load
        const int l = a - 192;
        sgix[0][l]      = grow0[l];
        sgix[0][64 + l] = grow0[64 + l];
    }
    __syncthreads();

    const uint4* shp = (const uint4*)s_xh_p + 16;    // 32 chunks of h
    const uint4* xwp = (const uint4*)sxw_p;          // 16 chunks of xw
    const uint4* whl = (const uint4*)whh_lds + (size_t)(wv * WHH_LC) * 64 + lane;

    for (int t = 0; t < SS; ++t) {
        const int p = t & 1;

        if (is_gate) {
            // ---- issue 8 stream loads (chunks 12..19) into wreg[8..15] ----
            wreg[8]  = whh_base[12 * 64]; wreg[9]  = whh_base[13 * 64];
            wreg[10] = whh_base[14 * 64]; wreg[11] = whh_base[15 * 64];
            wreg[12] = whh_base[16 * 64]; wreg[13] = whh_base[17 * 64];
            wreg[14] = whh_base[18 * 64]; wreg[15] = whh_base[19 * 64];
            // ---- 12 LDS-resident dots (2 chains) while loads fly ----
            float g0 = bias_h, g1 = 0.f;
            #pragma unroll
            for (int c = 0; c < WHH_LC; c += 2) {
                g0 = dot4(whl[(c + 0) * 64], shp[c + 0], g0);
                g1 = dot4(whl[(c + 1) * 64], shp[c + 1], g1);
            }
            // ---- consume 12..15; reissue 20..23 ----
            g0 = dot4(wreg[8],  shp[12], g0); g1 = dot4(wreg[9],  shp[13], g1);
            g0 = dot4(wreg[10], shp[14], g0); g1 = dot4(wreg[11], shp[15], g1);
            wreg[8]  = whh_base[20 * 64]; wreg[9]  = whh_base[21 * 64];
            wreg[10] = whh_base[22 * 64]; wreg[11] = whh_base[23 * 64];
            // ---- consume 16..19; reissue 24..27 ----
            g0 = dot4(wreg[12], shp[16], g0); g1 = dot4(wreg[13], shp[17], g1);
            g0 = dot4(wreg[14], shp[18], g0); g1 = dot4(wreg[15], shp[19], g1);
            wreg[12] = whh_base[24 * 64]; wreg[13] = whh_base[25 * 64];
            wreg[14] = whh_base[26 * 64]; wreg[15] = whh_base[27 * 64];
            // ---- consume 20..23; reissue 28..31 ----
            g0 = dot4(wreg[8],  shp[20], g0); g1 = dot4(wreg[9],  shp[21], g1);
            g0 = dot4(wreg[10], shp[22], g0); g1 = dot4(wreg[11], shp[23], g1);
            wreg[8]  = whh_base[28 * 64]; wreg[9]  = whh_base[29 * 64];
            wreg[10] = whh_base[30 * 64]; wreg[11] = whh_base[31 * 64];
            // ---- consume 24..27, then 28..31 ----
            g0 = dot4(wreg[12], shp[24], g0); g1 = dot4(wreg[13], shp[25], g1);
            g0 = dot4(wreg[14], shp[26], g0); g1 = dot4(wreg[15], shp[27], g1);
            g0 = dot4(wreg[8],  shp[28], g0); g1 = dot4(wreg[9],  shp[29], g1);
            g0 = dot4(wreg[10], shp[30], g0); g1 = dot4(wreg[11], shp[31], g1);
            sgh[tid] = g0 + g1;
            // wait for xw, then e5m2 Wih dot
            while (__hip_atomic_load(&flag_xw, __ATOMIC_ACQUIRE,
                                     __HIP_MEMORY_SCOPE_WORKGROUP) <= t) {}
            float q0 = bias_i, q1 = 0.f;
            #pragma unroll
            for (int c = 0; c < 8; ++c) {
                q0 = dot4f8w(wreg[c].x, wreg[c].y, xwp[2 * c + 0], q0);
                q1 = dot4f8w(wreg[c].z, wreg[c].w, xwp[2 * c + 1], q1);
            }
            sgi[tid] = q0 + q1;
        } else {
            // Wa_h score partials (reg-resident)
            float acc = 0.f;
            #pragma unroll
            for (int i = 0; i < 16; ++i) acc = dot4(wreg[i], shp[s * 16 + i], acc);
            sred[a] = acc;
            if (lane == 0)
                __hip_atomic_fetch_add(&flag_red, 1, __ATOMIC_ACQ_REL,
                                       __HIP_MEMORY_SCOPE_WORKGROUP);
            const int tgt = 4 * (t + 1);
            while (__hip_atomic_load(&flag_red, __ATOMIC_ACQUIRE,
                                     __HIP_MEMORY_SCOPE_WORKGROUP) < tgt) {}
            if (a < 64) {
                // wave 12: combine + tanh + softmax + packed xw
                float s_a = sred[lane] + sred[128 + lane] + sgix[p][lane] + ba_a;
                float s_b = sred[64 + lane] + sred[192 + lane] + sgix[p][64 + lane] + ba_b;
                s_a = tanhf(s_a); s_b = tanhf(s_b);
                float m = fmaxf(s_a, s_b);
                for (int off = 32; off; off >>= 1) m = fmaxf(m, __shfl_xor(m, off));
                float e_a = expf(s_a - m), e_b = expf(s_b - m);
                float sum = e_a + e_b;
                for (int off = 32; off; off >>= 1) sum += __shfl_xor(sum, off);
                float inv = 1.f / sum;
                float xa = e_a * inv * sx[p][lane];
                float xb = e_b * inv * sx[p][64 + lane];
                float xa1 = __shfl_down(xa, 1), xb1 = __shfl_down(xb, 1);
                if (!(lane & 1)) {
                    sxw_p[lane >> 1]        = pack2(xa, xa1);
                    sxw_p[32 + (lane >> 1)] = pack2(xb, xb1);
                }
                if (lane == 0)
                    __hip_atomic_store(&flag_xw, t + 1, __ATOMIC_RELEASE,
                                       __HIP_MEMORY_SCOPE_WORKGROUP);
            } else if (a >= 64 && a < 192 && t + 1 < SS) {
                // waves 13-14: prefetch x_{t+1}
                const int idx = a - 64;
                sx[p ^ 1][idx] = xrow[(t + 1) * II + idx];
            } else if (a >= 192 && t + 1 < SS) {
                // wave 15: prefetch gix_{t+1}
                const float* gr = grow0 + (size_t)(t + 1) * II;
                const int l = a - 192;
                sgix[p ^ 1][l]      = gr[l];
                sgix[p ^ 1][64 + l] = gr[64 + l];
            }
        }
        __syncthreads();                              // B1: gates done, x prefetched

        if (tid < HH) {
            const float r = 1.f / (1.f + expf(-(sgi[tid] + sgh[tid])));
            const float z = 1.f / (1.f + expf(-(sgi[tid + HH] + sgh[tid + HH])));
            const float n = tanhf(sgi[tid + 2 * HH] + r * sgh[tid + 2 * HH]);
            h_reg = (1.f - z) * n + z * h_reg;
            float hn2 = __shfl_down(h_reg, 1);
            if (!(tid & 1)) s_xh_p[64 + (tid >> 1)] = pack2(h_reg, hn2);
            float pd = wt_j * h_reg;
            for (int off = 32; off; off >>= 1) pd += __shfl_down(pd, off);
            if (lane == 0) swave[wv] = pd;
        }
        __syncthreads();                              // B2: h ready (loop barrier)

        if (tid < HH) {
            // redundant per-thread online softmax over time (no extra barrier)
            float dot = swave[0] + swave[1] + swave[2] + swave[3] + bt_r;
            float st = tanhf(dot);
            float mn = fmaxf(m_run, st);
            float aa = expf(m_run - mn), ww = expf(st - mn);
            l_run = l_run * aa + ww;
            m_run = mn;
            c_reg = c_reg * aa + ww * h_reg;
        }
    }

    __syncthreads();
    if (tid < HH) {
        float ctx = c_reg / l_run;
        float pd = wf_j * ctx;
        for (int off = 32; off; off >>= 1) pd += __shfl_down(pd, off);
        if (lane == 0) swave[wv] = pd;
    }
    __syncthreads();
    if (tid == 0) {
        float logit = swave[0] + swave[1] + swave[2] + swave[3] + h2f(wsb[OFF_BF]);
        out[b] = 1.f / (1.f + expf(-logit));
    }
}

// ============ single-row fallback (R4 structure, GIX=0 path) ============
template <int GIX>
__global__ __launch_bounds__(1024, 4) void da_rnn_kernel(
    const float* __restrict__ x, const ushort_t* __restrict__ wsb,
    const float* __restrict__ gix, float* __restrict__ out)
{
    const int b    = blockIdx.x;
    const int tid  = threadIdx.x;
    const int lane = tid & 63;
    const int wv   = tid >> 6;
    const bool is_gate = (tid < 3 * HH);

    __shared__ __align__(16) uint32 whh_lds[WHH_LC * 768 * 4];
    __shared__ __align__(16) uint32 s_xh_p[192];
    __shared__ __align__(16) uint32 sxw_p[64];
    __shared__ __align__(16) float  sred[256];
    __shared__ __align__(16) float  sgi[3 * HH];
    __shared__ __align__(16) float  sgh[3 * HH];
    __shared__ __align__(16) float  sx[2][II];
    __shared__ __align__(16) float  sgix[2][II];
    __shared__ float swave[4];
    __shared__ int   flag_red;
    __shared__ int   flag_xw;

    if (tid == 0) { flag_red = 0; flag_xw = 0; }
    if (tid < II) s_xh_p[64 + tid] = 0u;

    uint4 wreg[16];
    const int a   = tid - 3 * HH;
    const int row = a & 127;
    const int s   = a >> 7;
    const uint4* whh_base = (const uint4*)(wsb + OFF_WHH) + (size_t)wv * 32 * 64 + lane;
    const uint4* wa_st = nullptr;
    float bias_i = 0.f, bias_h = 0.f, ba_a = 0.f, ba_b = 0.f;

    if (is_gate) {
        const uint4* wih_g = (const uint4*)(wsb + OFF_WIH) + (size_t)wv * 16 * 64 + lane;
        #pragma unroll
        for (int c = 0; c < 16; ++c) wreg[c] = wih_g[c * 64];
        bias_i = h2f(wsb[OFF_BIH + tid]);
        bias_h = h2f(wsb[OFF_BHH + tid]);
        #pragma unroll
        for (int c = 0; c < WHH_LC; ++c)
            ((uint4*)whh_lds)[(wv * WHH_LC + c) * 64 + lane] = whh_base[c * 64];
    } else {
        if (GIX) {
            const uint4* wah_g = (const uint4*)(wsb + OFF_WAH);
            const size_t gbh = ((size_t)(row >> 6) * 32 + s * 16) * 64 + (row & 63);
            #pragma unroll
            for (int i = 0; i < 16; ++i) wreg[i] = wah_g[gbh + (size_t)i * 64];
        } else {
            const uint4* wa_g = (const uint4*)(wsb + OFF_WA);
            const size_t gbase = ((size_t)(row >> 6) * 48 + s * 24) * 64 + (row & 63);
            #pragma unroll
            for (int i = 0; i < 16; ++i) wreg[i] = wa_g[gbase + (size_t)i * 64];
            wa_st = wa_g + gbase + (size_t)16 * 64;
        }
        ba_a = h2f(wsb[OFF_BA + lane]);
        ba_b = h2f(wsb[OFF_BA + 64 + lane]);
    }

    float h_reg = 0.f, c_reg = 0.f, m_run = -2.0f, l_run = 0.f;
    float wt_j = 0.f, wf_j = 0.f, bt_r = 0.f;
    if (tid < HH) {
        wt_j = h2f(wsb[OFF_WT + tid]);
        wf_j = h2f(wsb[OFF_WF + tid]);
        bt_r = h2f(wsb[OFF_BT]);
    }

    const float* xrow  = x + (size_t)b * SS * II;
    const float* grow0 = GIX ? (gix + (size_t)b * SS * II) : nullptr;
    if (!is_gate && a >= 64 && a < 192) {
        const int idx = a - 64;
        float v = xrow[idx];
        sx[0][idx] = v;
        if (!GIX) {
            float vn = __shfl_down(v, 1);
            if (!(idx & 1)) s_xh_p[idx >> 1] = pack2(v, vn);
        }
    }
    if (GIX && !is_gate && a >= 192) {
        const int l = a - 192;
        sgix[0][l]      = grow0[l];
        sgix[0][64 + l] = grow0[64 + l];
    }
    __syncthreads();

    const uint4* st4 = (const uint4*)s_xh_p;
    const uint4* shp = (const uint4*)s_xh_p + 16;
    const uint4* xwp = (const uint4*)sxw_p;
    const uint4* whl = (const uint4*)whh_lds + (size_t)(wv * WHH_LC) * 64 + lane;

    for (int t = 0; t < SS; ++t) {
        const int p = t & 1;

        if (is_gate) {
            float gh = bias_h;
            #pragma unroll
            for (int c = 0; c < WHH_LC; ++c) gh = dot4(whl[c * 64], shp[c], gh);
            #pragma unroll 4
            for (int c = WHH_LC; c < 32; ++c) gh = dot4(whh_base[c * 64], shp[c], gh);
            sgh[tid] = gh;
            while (__hip_atomic_load(&flag_xw, __ATOMIC_ACQUIRE,
                                     __HIP_MEMORY_SCOPE_WORKGROUP) <= t) {}
            float gi = bias_i;
            #pragma unroll
            for (int c = 0; c < 16; ++c) gi = dot4(wreg[c], xwp[c], gi);
            sgi[tid] = gi;
        } else {
            float acc;
            if (GIX) {
                acc = 0.f;
                #pragma unroll
                for (int i = 0; i < 16; ++i) acc = dot4(wreg[i], shp[s * 16 + i], acc);
            } else {
                acc = 0.f;
                #pragma unroll
                for (int i = 0; i < 16; ++i) acc = dot4(wreg[i], st4[s * 24 + i], acc);
                #pragma unroll 4
                for (int i = 0; i < 8; ++i) acc = dot4(wa_st[i * 64], st4[s * 24 + 16 + i], acc);
            }
            sred[a] = acc;
            if (lane == 0)
                __hip_atomic_fetch_add(&flag_red, 1, __ATOMIC_ACQ_REL,
                                       __HIP_MEMORY_SCOPE_WORKGROUP);
            const int tgt = 4 * (t + 1);
            while (__hip_atomic_load(&flag_red, __ATOMIC_ACQUIRE,
                                     __HIP_MEMORY_SCOPE_WORKGROUP) < tgt) {}
            if (a < 64) {
                float s_a = sred[lane] + sred[128 + lane] + ba_a;
                float s_b = sred[64 + lane] + sred[192 + lane] + ba_b;
                if (GIX) { s_a += sgix[p][lane]; s_b += sgix[p][64 + lane]; }
                s_a = tanhf(s_a); s_b = tanhf(s_b);
                float m = fmaxf(s_a, s_b);
                for (int off = 32; off; off >>= 1) m = fmaxf(m, __shfl_xor(m, off));
                float e_a = expf(s_a - m), e_b = expf(s_b - m);
                float sum = e_a + e_b;
                for (int off = 32; off; off >>= 1) sum += __shfl_xor(sum, off);
                float inv = 1.f / sum;
                float xa = e_a * inv * sx[p][lane];
                float xb = e_b * inv * sx[p][64 + lane];
                float xa1 = __shfl_down(xa, 1), xb1 = __shfl_down(xb, 1);
                if (!(lane & 1)) {
                    sxw_p[lane >> 1]        = pack2(xa, xa1);
                    sxw_p[32 + (lane >> 1)] = pack2(xb, xb1);
                }
                if (lane == 0)
                    __hip_atomic_store(&flag_xw, t + 1, __ATOMIC_RELEASE,
                                       __HIP_MEMORY_SCOPE_WORKGROUP);
            } else if (a >= 64 && a < 192 && t + 1 < SS) {
                const int idx = a - 64;
                float v = xrow[(t + 1) * II + idx];
                sx[p ^ 1][idx] = v;
                if (!GIX) {
                    float vn = __shfl_down(v, 1);
                    if (!(idx & 1)) s_xh_p[idx >> 1] = pack2(v, vn);
                }
            } else if (GIX && a >= 192 && t + 1 < SS) {
                const float* gr = grow0 + (size_t)(t + 1) * II;
                const int l = a - 192;
                sgix[p ^ 1][l]      = gr[l];
                sgix[p ^ 1][64 + l] = gr[64 + l];
            }
        }
        __syncthreads();

        if (tid < HH) {
            const float r = 1.f / (1.f + expf(-(sgi[tid] + sgh[tid])));
            const float z = 1.f / (1.f + expf(-(sgi[tid + HH] + sgh[tid + HH])));
            const float n = tanhf(sgi[tid + 2 * HH] + r * sgh[tid + 2 * HH]);
            h_reg = (1.f - z) * n + z * h_reg;
            float hn2 = __shfl_down(h_reg, 1);
            if (!(tid & 1)) s_xh_p[64 + (tid >> 1)] = pack2(h_reg, hn2);
            float pd = wt_j * h_reg;
            for (int off = 32; off; off >>= 1) pd += __shfl_down(pd, off);
            if (lane == 0) swave[wv] = pd;
        }
        __syncthreads();

        if (tid < HH) {
            float dot = swave[0] + swave[1] + swave[2] + swave[3] + bt_r;
            float st = tanhf(dot);
            float mn = fmaxf(m_run, st);
            float aa = expf(m_run - mn), ww = expf(st - mn);
            l_run = l_run * aa + ww;
            m_run = mn;
            c_reg = c_reg * aa + ww * h_reg;
        }
    }

    __syncthreads();
    if (tid < HH) {
        float ctx = c_reg / l_run;
        float pd = wf_j * ctx;
        for (int off = 32; off; off >>= 1) pd += __shfl_down(pd, off);
        if (lane == 0) swave[wv] = pd;
    }
    __syncthreads();
    if (tid == 0) {
        float logit = swave[0] + swave[1] + swave[2] + swave[3] + h2f(wsb[OFF_BF]);
        out[b] = 1.f / (1.f + expf(-logit));
    }
}

extern "C" void kernel_launch(void* const* d_in, const int* in_sizes, int n_in,
                              void* d_out, int out_size, void* d_ws, size_t ws_size,
                              hipStream_t stream) {
    ushort_t* wsb = (ushort_t*)d_ws;
    const size_t WS_NEED = (size_t)OFF_GIX * 2 + (size_t)BB * SS * II * 4;
    const bool use_gix = ws_size >= WS_NEED;

    cvt_swz<<<dim3((128 * 48 + 255) / 256), dim3(256), 0, stream>>>(
        (const float*)d_in[1], wsb + OFF_WA, 128, 48, 384, 0);       // W_a  [128,384]
    cvt_swz<<<dim3((768 * 16 + 255) / 256), dim3(256), 0, stream>>>(
        (const float*)d_in[3], wsb + OFF_WIH, 768, 16, 128, 0);      // W_ih [768,128]
    cvt_swz<<<dim3((768 * 32 + 255) / 256), dim3(256), 0, stream>>>(
        (const float*)d_in[5], wsb + OFF_WHH, 768, 32, 256, 0);      // W_hh [768,256]
    if (use_gix) {
        cvt_swz<<<dim3((128 * 32 + 255) / 256), dim3(256), 0, stream>>>(
            (const float*)d_in[1], wsb + OFF_WAH, 128, 32, 384, 128); // W_a h-part
        cvt_swz8<<<dim3((768 * 16 + 255) / 256), dim3(256), 0, stream>>>(
            (const float*)d_in[3], wsb + OFF_WIH8, 768, 16, 128, 0);  // W_ih e5m2
    }

    struct { int src_idx; int off; int n; } cv[7] = {
        {2, OFF_BA,  II}, {4, OFF_BIH, 3 * HH}, {6, OFF_BHH, 3 * HH},
        {7, OFF_WT,  HH}, {8, OFF_BT, 1}, {9, OFF_WF, HH}, {10, OFF_BF, 1},
    };
    for (int i = 0; i < 7; ++i) {
        int blocks = (cv[i].n + 255) / 256;
        cvt_f32_f16<<<dim3(blocks), dim3(256), 0, stream>>>(
            (const float*)d_in[cv[i].src_idx], wsb + cv[i].off, cv[i].n);
    }

    float* gixf = (float*)(wsb + OFF_GIX);
    if (use_gix) {
        gix_kernel<<<dim3(BB), dim3(512), 0, stream>>>(
            (const float*)d_in[0], wsb, gixf);
        da_rnn_pf_kernel<<<dim3(BB), dim3(1024), 0, stream>>>(
            (const float*)d_in[0], wsb, gixf, (float*)d_out);
    } else {
        da_rnn_kernel<0><<<dim3(BB), dim3(1024), 0, stream>>>(
            (const float*)d_in[0], wsb, nullptr, (float*)d_out);
    }
}

// Round 11
// 5115.564 us; speedup vs baseline: 1.4123x; 1.4123x over previous
//
#include <hip/hip_runtime.h>
#include <math.h>

#define BB 256
#define SS 512
#define II 128
#define HH 256

typedef unsigned short ushort_t;
typedef unsigned int uint32;

// d_ws f16 blob element offsets (each a multiple of 8 -> 16B aligned)
#define OFF_WA   0          // 128*384 = 49152   (swizzled, 48 chunks)
#define OFF_BA   49152      // 128
#define OFF_WIH  49280      // 768*128 = 98304   (swizzled, 16 chunks)
#define OFF_BIH  147584     // 768
#define OFF_WHH  148352     // 768*256 = 196608  (swizzled, 32 chunks)
#define OFF_BHH  344960     // 768
#define OFF_WT   345728     // 256
#define OFF_BT   345984     // 1 (padded to 8)
#define OFF_WF   345992     // 256
#define OFF_BF   346248     // 1 (padded to 8)
#define OFF_WAH  346256     // 128*256 = 32768   (Wa h-part only, swizzled, 32 chunks)
#define OFF_WIH8 379024     // Wih in e5m2: 768 rows x 16 chunks x 8 B = 49152 ushort units
#define OFF_GIX  428176     // fp32 [B,S,128] precomputed Wa_x . x_t

#define WHH_LC   12   // chunks of Whh resident in LDS (144 KB)

// ---------- f16 helpers ----------
__device__ __forceinline__ float h2f(ushort_t u) {
    union { ushort_t s[2]; _Float16 h[2]; } v; v.s[0] = u; return (float)v.h[0];
}
__device__ __forceinline__ ushort_t f2h(float f) {
    union { _Float16 h; ushort_t s; } v; v.h = (_Float16)f; return v.s;
}
__device__ __forceinline__ uint32 pack2(float a, float b) {
    union { _Float16 h[2]; uint32 u; } v;
    v.h[0] = (_Float16)a; v.h[1] = (_Float16)b; return v.u;
}
// f16 -> e5m2 byte (top byte of f16, RNE on the 8 dropped mantissa bits).
__device__ __forceinline__ uint32 f2e5m2(float f) {
    uint32 t = (uint32)f2h(f);
    return ((t + 0x7Fu + ((t >> 8) & 1u)) >> 8) & 0xFFu;
}

// packed-f16 dual-MAC: v_dot2_f32_f16 if available, unpack+fma fallback
#if __has_builtin(__builtin_amdgcn_fdot2)
typedef _Float16 v2h __attribute__((ext_vector_type(2)));
__device__ __forceinline__ float dot2u(uint32 w, uint32 v, float acc) {
    return __builtin_amdgcn_fdot2(
        __builtin_bit_cast(v2h, w), __builtin_bit_cast(v2h, v), acc, false);
}
#else
__device__ __forceinline__ float dot2u(uint32 w, uint32 v, float acc) {
    union { uint32 u; _Float16 h[2]; } a, b; a.u = w; b.u = v;
    acc = fmaf((float)a.h[0], (float)b.h[0], acc);
    return fmaf((float)a.h[1], (float)b.h[1], acc);
}
#endif
__device__ __forceinline__ float dot4(uint4 w, uint4 v, float acc) {
    acc = dot2u(w.x, v.x, acc); acc = dot2u(w.y, v.y, acc);
    acc = dot2u(w.z, v.z, acc); return dot2u(w.w, v.w, acc);
}

// e5m2 x4 (one uint32) -> two packed-f16 pairs via byte permute (b<<8 == f16)
#if __has_builtin(__builtin_amdgcn_perm)
__device__ __forceinline__ uint32 e5m2_lo(uint32 w) {    // bytes [0,b0,0,b1]
    return __builtin_amdgcn_perm(0u, w, 0x010c000cu);
}
__device__ __forceinline__ uint32 e5m2_hi(uint32 w) {    // bytes [0,b2,0,b3]
    return __builtin_amdgcn_perm(0u, w, 0x030c020cu);
}
#else
__device__ __forceinline__ uint32 e5m2_lo(uint32 w) {
    return ((w & 0xFFu) << 8) | ((w & 0xFF00u) << 16);
}
__device__ __forceinline__ uint32 e5m2_hi(uint32 w) {
    return ((w >> 16) & 0xFFu) << 8 | (w & 0xFF000000u);
}
#endif
// 8 e5m2 weights (as 2x uint32) . 8 f16 activations (uint4)
__device__ __forceinline__ float dot4f8w(uint32 wlo, uint32 whi, uint4 v, float acc) {
    acc = dot2u(e5m2_lo(wlo), v.x, acc);
    acc = dot2u(e5m2_hi(wlo), v.y, acc);
    acc = dot2u(e5m2_lo(whi), v.z, acc);
    return dot2u(e5m2_hi(whi), v.w, acc);
}

// workgroup barrier WITHOUT vmcnt drain (proven correct in this kernel family:
// all cross-wave data flows through LDS and is lgkm-fenced; per-wave global
// loads are ordered by the wave's own vmcnt at their consumption point).
__device__ __forceinline__ void barrier_soft() {
    asm volatile("s_waitcnt lgkmcnt(0)" ::: "memory");
    __builtin_amdgcn_s_barrier();
    asm volatile("" ::: "memory");
}

__global__ void cvt_f32_f16(const float* __restrict__ src, ushort_t* __restrict__ dst, int n) {
    int i = blockIdx.x * 256 + threadIdx.x;
    if (i < n) dst[i] = f2h(src[i]);
}

// Swizzled fp32 -> f16: uint4 index = ((row/64)*chunks + c)*64 + (row%64)
__global__ void cvt_swz(const float* __restrict__ src, ushort_t* __restrict__ dst,
                        int rows, int chunks, int srcStride, int colOff) {
    int t = blockIdx.x * 256 + threadIdx.x;
    if (t >= rows * chunks) return;
    int row = t / chunks, c = t % chunks;
    const float* s = src + (size_t)row * srcStride + colOff + c * 8;
    uint4 v;
    v.x = pack2(s[0], s[1]); v.y = pack2(s[2], s[3]);
    v.z = pack2(s[4], s[5]); v.w = pack2(s[6], s[7]);
    ((uint4*)dst)[((size_t)(row >> 6) * chunks + c) * 64 + (row & 63)] = v;
}

// Swizzled fp32 -> e5m2 (8 weights -> uint2), same swizzle in uint2 units.
__global__ void cvt_swz8(const float* __restrict__ src, ushort_t* __restrict__ dst,
                         int rows, int chunks, int srcStride, int colOff) {
    int t = blockIdx.x * 256 + threadIdx.x;
    if (t >= rows * chunks) return;
    int row = t / chunks, c = t % chunks;
    const float* s = src + (size_t)row * srcStride + colOff + c * 8;
    uint2 v;
    v.x = f2e5m2(s[0]) | (f2e5m2(s[1]) << 8) | (f2e5m2(s[2]) << 16) | (f2e5m2(s[3]) << 24);
    v.y = f2e5m2(s[4]) | (f2e5m2(s[5]) << 8) | (f2e5m2(s[6]) << 16) | (f2e5m2(s[7]) << 24);
    ((uint2*)dst)[((size_t)(row >> 6) * chunks + c) * 64 + (row & 63)] = v;
}

// Pre-pass: gix[b,t,i] = dot(Wa_x[i,:], x[b,t,:])  (h-independent, hoisted).
__global__ __launch_bounds__(512, 2) void gix_kernel(
    const float* __restrict__ x, const ushort_t* __restrict__ wsb,
    float* __restrict__ gix)
{
    const int b = blockIdx.x, tid = threadIdx.x;
    const int r4 = tid >> 7, i = tid & 127;
    __shared__ __align__(16) uint32 sxp[4][64];

    uint4 w[16];
    const uint4* wa_g = (const uint4*)(wsb + OFF_WA);
    const size_t gb = (size_t)(i >> 6) * 48 * 64 + (i & 63);
    #pragma unroll
    for (int c = 0; c < 16; ++c) w[c] = wa_g[gb + (size_t)c * 64];

    const float* xb = x + (size_t)b * SS * II;
    float* gout = gix + (size_t)b * SS * II;
    for (int j = 0; j < SS; j += 4) {
        float v = xb[(j + r4) * II + i];
        float vn = __shfl_down(v, 1);
        if (!(i & 1)) sxp[r4][i >> 1] = pack2(v, vn);
        __syncthreads();
        const uint4* sx4 = (const uint4*)sxp[r4];
        float acc = 0.f;
        #pragma unroll
        for (int c = 0; c < 16; ++c) acc = dot4(w[c], sx4[c], acc);
        gout[(j + r4) * II + i] = acc;
        __syncthreads();
    }
}

// ============ main kernel: wave-specialized split loops ============
// One block (1024 threads) per batch row. The gate and attn roles run
// SEPARATE loops (wave-uniform branch, matching 2 barriers/iteration) so each
// gets independent register allocation — no shared role-overlaid array.
// Gate waves 0-11: Wih in e5m2 (8 uint4, 32 regs, read-only -> AGPR-able);
//   the ~32 freed ARCH VGPRs fund an 8-deep p/q load pipeline for the 20
//   streamed Whh chunks (plain locals — rewritten freely, never AGPRs).
//   p refilled for step t+1 right after gi -> latency hides under B1/B2.
// Attn waves 12-15: exactly R4 — Wa_h f16 reg-resident, wave12 softmax,
//   waves 13-14 x prefetch, wave 15 gix prefetch.
__global__ __launch_bounds__(1024, 4) void da_rnn_ws_kernel(
    const float* __restrict__ x,          // fp32 [B,S,I]
    const ushort_t* __restrict__ wsb,     // f16/e5m2 blob in d_ws
    const float* __restrict__ gix,        // fp32 [B,S,I] precomputed
    float* __restrict__ out)              // fp32 [B,1]
{
    const int b    = blockIdx.x;
    const int tid  = threadIdx.x;
    const int lane = tid & 63;
    const int wv   = tid >> 6;
    const bool is_gate = (tid < 3 * HH);

    __shared__ __align__(16) uint32 whh_lds[WHH_LC * 768 * 4];  // 144 KB
    __shared__ __align__(16) uint32 s_xh_p[192];     // packed f16 [x_t(128); h(256)]
    __shared__ __align__(16) uint32 sxw_p[64];       // packed f16 alpha*x_t
    __shared__ __align__(16) float  sred[256];
    __shared__ __align__(16) float  sgi[3 * HH];
    __shared__ __align__(16) float  sgh[3 * HH];
    __shared__ __align__(16) float  sx[2][II];
    __shared__ __align__(16) float  sgix[2][II];
    __shared__ float swave[4];
    __shared__ int   flag_red;
    __shared__ int   flag_xw;

    if (tid == 0) { flag_red = 0; flag_xw = 0; }
    if (tid < II) s_xh_p[64 + tid] = 0u;             // h_0 = 0 (packed)

    float h_reg = 0.f, c_reg = 0.f, m_run = -2.0f, l_run = 0.f;
    float wt_j = 0.f, wf_j = 0.f, bt_r = 0.f;
    if (tid < HH) {
        wt_j = h2f(wsb[OFF_WT + tid]);
        wf_j = h2f(wsb[OFF_WF + tid]);
        bt_r = h2f(wsb[OFF_BT]);
    }

    const uint4* shp = (const uint4*)s_xh_p + 16;    // 32 chunks of h
    const uint4* xwp = (const uint4*)sxw_p;          // 16 chunks of xw

    if (is_gate) {
        // ================= GATE role: waves 0-11 =================
        const uint4* whh_base = (const uint4*)(wsb + OFF_WHH)
                              + (size_t)wv * 32 * 64 + lane;
        uint4 wih8[8];                               // Wih e5m2, read-only
        {
            const uint2* w8 = (const uint2*)(wsb + OFF_WIH8)
                            + (size_t)wv * 16 * 64 + lane;
            #pragma unroll
            for (int c = 0; c < 8; ++c) {
                uint2 lo = w8[(2 * c) * 64];
                uint2 hi = w8[(2 * c + 1) * 64];
                wih8[c].x = lo.x; wih8[c].y = lo.y;
                wih8[c].z = hi.x; wih8[c].w = hi.y;
            }
        }
        const float bias_i = h2f(wsb[OFF_BIH + tid]);
        const float bias_h = h2f(wsb[OFF_BHH + tid]);
        #pragma unroll
        for (int c = 0; c < WHH_LC; ++c)
            ((uint4*)whh_lds)[(wv * WHH_LC + c) * 64 + lane] = whh_base[c * 64];
        const uint4* whl = (const uint4*)whh_lds + (size_t)(wv * WHH_LC) * 64 + lane;
        __syncthreads();                              // init barrier (matches attn)

        // prime p = chunks 12..15
        uint4 p0 = whh_base[12 * 64], p1 = whh_base[13 * 64];
        uint4 p2 = whh_base[14 * 64], p3 = whh_base[15 * 64];

        for (int t = 0; t < SS; ++t) {
            // issue q = chunks 16..19 (8 loads now in flight with p)
            uint4 q0 = whh_base[16 * 64], q1 = whh_base[17 * 64];
            uint4 q2 = whh_base[18 * 64], q3 = whh_base[19 * 64];
            // 12 LDS-resident dots (4 chains) while loads fly
            float g0 = bias_h, g1 = 0.f, g2 = 0.f, g3 = 0.f;
            #pragma unroll
            for (int c = 0; c < WHH_LC; c += 4) {
                g0 = dot4(whl[(c + 0) * 64], shp[c + 0], g0);
                g1 = dot4(whl[(c + 1) * 64], shp[c + 1], g1);
                g2 = dot4(whl[(c + 2) * 64], shp[c + 2], g2);
                g3 = dot4(whl[(c + 3) * 64], shp[c + 3], g3);
            }
            // consume p(12..15); reissue p = 20..23
            g0 = dot4(p0, shp[12], g0); g1 = dot4(p1, shp[13], g1);
            g2 = dot4(p2, shp[14], g2); g3 = dot4(p3, shp[15], g3);
            p0 = whh_base[20 * 64]; p1 = whh_base[21 * 64];
            p2 = whh_base[22 * 64]; p3 = whh_base[23 * 64];
            // consume q(16..19); reissue q = 24..27
            g0 = dot4(q0, shp[16], g0); g1 = dot4(q1, shp[17], g1);
            g2 = dot4(q2, shp[18], g2); g3 = dot4(q3, shp[19], g3);
            q0 = whh_base[24 * 64]; q1 = whh_base[25 * 64];
            q2 = whh_base[26 * 64]; q3 = whh_base[27 * 64];
            // consume p(20..23); reissue p = 28..31
            g0 = dot4(p0, shp[20], g0); g1 = dot4(p1, shp[21], g1);
            g2 = dot4(p2, shp[22], g2); g3 = dot4(p3, shp[23], g3);
            p0 = whh_base[28 * 64]; p1 = whh_base[29 * 64];
            p2 = whh_base[30 * 64]; p3 = whh_base[31 * 64];
            // consume q(24..27), then p(28..31)
            g0 = dot4(q0, shp[24], g0); g1 = dot4(q1, shp[25], g1);
            g2 = dot4(q2, shp[26], g2); g3 = dot4(q3, shp[27], g3);
            g0 = dot4(p0, shp[28], g0); g1 = dot4(p1, shp[29], g1);
            g2 = dot4(p2, shp[30], g2); g3 = dot4(p3, shp[31], g3);
            sgh[tid] = (g0 + g1) + (g2 + g3);
            // wait for xw, then e5m2 Wih dot
            while (__hip_atomic_load(&flag_xw, __ATOMIC_ACQUIRE,
                                     __HIP_MEMORY_SCOPE_WORKGROUP) <= t) {}
            float q0f = bias_i, q1f = 0.f;
            #pragma unroll
            for (int c = 0; c < 8; ++c) {
                q0f = dot4f8w(wih8[c].x, wih8[c].y, xwp[2 * c + 0], q0f);
                q1f = dot4f8w(wih8[c].z, wih8[c].w, xwp[2 * c + 1], q1f);
            }
            sgi[tid] = q0f + q1f;
            // refill p = chunks 12..15 for step t+1 (latency hides under B1/B2)
            p0 = whh_base[12 * 64]; p1 = whh_base[13 * 64];
            p2 = whh_base[14 * 64]; p3 = whh_base[15 * 64];

            barrier_soft();                           // B1
            if (tid < HH) {
                const float r = 1.f / (1.f + expf(-(sgi[tid] + sgh[tid])));
                const float z = 1.f / (1.f + expf(-(sgi[tid + HH] + sgh[tid + HH])));
                const float n = tanhf(sgi[tid + 2 * HH] + r * sgh[tid + 2 * HH]);
                h_reg = (1.f - z) * n + z * h_reg;
                float hn2 = __shfl_down(h_reg, 1);
                if (!(tid & 1)) s_xh_p[64 + (tid >> 1)] = pack2(h_reg, hn2);
                float pd = wt_j * h_reg;
                for (int off = 32; off; off >>= 1) pd += __shfl_down(pd, off);
                if (lane == 0) swave[wv] = pd;
            }
            barrier_soft();                           // B2
            if (tid < HH) {
                float dot = swave[0] + swave[1] + swave[2] + swave[3] + bt_r;
                float st = tanhf(dot);
                float mn = fmaxf(m_run, st);
                float aa = expf(m_run - mn), ww = expf(st - mn);
                l_run = l_run * aa + ww;
                m_run = mn;
                c_reg = c_reg * aa + ww * h_reg;
            }
        }
    } else {
        // ================= ATTN role: waves 12-15 =================
        const int a   = tid - 3 * HH;                // 0..255
        const int row = a & 127;
        const int s   = a >> 7;
        uint4 wah[16];
        {
            const uint4* wah_g = (const uint4*)(wsb + OFF_WAH);
            const size_t gbh = ((size_t)(row >> 6) * 32 + s * 16) * 64 + (row & 63);
            #pragma unroll
            for (int i = 0; i < 16; ++i) wah[i] = wah_g[gbh + (size_t)i * 64];
        }
        const float ba_a = h2f(wsb[OFF_BA + lane]);
        const float ba_b = h2f(wsb[OFF_BA + 64 + lane]);
        const float* xrow  = x   + (size_t)b * SS * II;
        const float* grow0 = gix + (size_t)b * SS * II;
        if (a >= 64 && a < 192) {                    // x_0 load
            const int idx = a - 64;
            sx[0][idx] = xrow[idx];
        }
        if (a >= 192) {                              // gix_0 load
            const int l = a - 192;
            sgix[0][l]      = grow0[l];
            sgix[0][64 + l] = grow0[64 + l];
        }
        __syncthreads();                              // init barrier (matches gate)

        for (int t = 0; t < SS; ++t) {
            const int p = t & 1;
            float acc = 0.f;
            #pragma unroll
            for (int i = 0; i < 16; ++i) acc = dot4(wah[i], shp[s * 16 + i], acc);
            sred[a] = acc;
            if (lane == 0)
                __hip_atomic_fetch_add(&flag_red, 1, __ATOMIC_ACQ_REL,
                                       __HIP_MEMORY_SCOPE_WORKGROUP);
            const int tgt = 4 * (t + 1);
            while (__hip_atomic_load(&flag_red, __ATOMIC_ACQUIRE,
                                     __HIP_MEMORY_SCOPE_WORKGROUP) < tgt) {}
            if (a < 64) {
                // wave 12: combine + tanh + softmax + packed xw
                float s_a = sred[lane] + sred[128 + lane] + sgix[p][lane] + ba_a;
                float s_b = sred[64 + lane] + sred[192 + lane] + sgix[p][64 + lane] + ba_b;
                s_a = tanhf(s_a); s_b = tanhf(s_b);
                float m = fmaxf(s_a, s_b);
                for (int off = 32; off; off >>= 1) m = fmaxf(m, __shfl_xor(m, off));
                float e_a = expf(s_a - m), e_b = expf(s_b - m);
                float sum = e_a + e_b;
                for (int off = 32; off; off >>= 1) sum += __shfl_xor(sum, off);
                float inv = 1.f / sum;
                float xa = e_a * inv * sx[p][lane];
                float xb = e_b * inv * sx[p][64 + lane];
                float xa1 = __shfl_down(xa, 1), xb1 = __shfl_down(xb, 1);
                if (!(lane & 1)) {
                    sxw_p[lane >> 1]        = pack2(xa, xa1);
                    sxw_p[32 + (lane >> 1)] = pack2(xb, xb1);
                }
                if (lane == 0)
                    __hip_atomic_store(&flag_xw, t + 1, __ATOMIC_RELEASE,
                                       __HIP_MEMORY_SCOPE_WORKGROUP);
            } else if (a >= 64 && a < 192 && t + 1 < SS) {
                // waves 13-14: prefetch x_{t+1}
                const int idx = a - 64;
                sx[p ^ 1][idx] = xrow[(t + 1) * II + idx];
            } else if (a >= 192 && t + 1 < SS) {
                // wave 15: prefetch gix_{t+1}
                const float* gr = grow0 + (size_t)(t + 1) * II;
                const int l = a - 192;
                sgix[p ^ 1][l]      = gr[l];
                sgix[p ^ 1][64 + l] = gr[64 + l];
            }
            barrier_soft();                           // B1
            barrier_soft();                           // B2
        }
    }

    __syncthreads();
    if (tid < HH) {
        float ctx = c_reg / l_run;
        float pd = wf_j * ctx;
        for (int off = 32; off; off >>= 1) pd += __shfl_down(pd, off);
        if (lane == 0) swave[wv] = pd;
    }
    __syncthreads();
    if (tid == 0) {
        float logit = swave[0] + swave[1] + swave[2] + swave[3] + h2f(wsb[OFF_BF]);
        out[b] = 1.f / (1.f + expf(-logit));
    }
}

// ============ single-row fallback (R4 structure, GIX=0 path) ============
template <int GIX>
__global__ __launch_bounds__(1024, 4) void da_rnn_kernel(
    const float* __restrict__ x, const ushort_t* __restrict__ wsb,
    const float* __restrict__ gix, float* __restrict__ out)
{
    const int b    = blockIdx.x;
    const int tid  = threadIdx.x;
    const int lane = tid & 63;
    const int wv   = tid >> 6;
    const bool is_gate = (tid < 3 * HH);

    __shared__ __align__(16) uint32 whh_lds[WHH_LC * 768 * 4];
    __shared__ __align__(16) uint32 s_xh_p[192];
    __shared__ __align__(16) uint32 sxw_p[64];
    __shared__ __align__(16) float  sred[256];
    __shared__ __align__(16) float  sgi[3 * HH];
    __shared__ __align__(16) float  sgh[3 * HH];
    __shared__ __align__(16) float  sx[2][II];
    __shared__ __align__(16) float  sgix[2][II];
    __shared__ float swave[4];
    __shared__ int   flag_red;
    __shared__ int   flag_xw;

    if (tid == 0) { flag_red = 0; flag_xw = 0; }
    if (tid < II) s_xh_p[64 + tid] = 0u;

    uint4 wreg[16];
    const int a   = tid - 3 * HH;
    const int row = a & 127;
    const int s   = a >> 7;
    const uint4* whh_base = (const uint4*)(wsb + OFF_WHH) + (size_t)wv * 32 * 64 + lane;
    const uint4* wa_st = nullptr;
    float bias_i = 0.f, bias_h = 0.f, ba_a = 0.f, ba_b = 0.f;

    if (is_gate) {
        const uint4* wih_g = (const uint4*)(wsb + OFF_WIH) + (size_t)wv * 16 * 64 + lane;
        #pragma unroll
        for (int c = 0; c < 16; ++c) wreg[c] = wih_g[c * 64];
        bias_i = h2f(wsb[OFF_BIH + tid]);
        bias_h = h2f(wsb[OFF_BHH + tid]);
        #pragma unroll
        for (int c = 0; c < WHH_LC; ++c)
            ((uint4*)whh_lds)[(wv * WHH_LC + c) * 64 + lane] = whh_base[c * 64];
    } else {
        if (GIX) {
            const uint4* wah_g = (const uint4*)(wsb + OFF_WAH);
            const size_t gbh = ((size_t)(row >> 6) * 32 + s * 16) * 64 + (row & 63);
            #pragma unroll
            for (int i = 0; i < 16; ++i) wreg[i] = wah_g[gbh + (size_t)i * 64];
        } else {
            const uint4* wa_g = (const uint4*)(wsb + OFF_WA);
            const size_t gbase = ((size_t)(row >> 6) * 48 + s * 24) * 64 + (row & 63);
            #pragma unroll
            for (int i = 0; i < 16; ++i) wreg[i] = wa_g[gbase + (size_t)i * 64];
            wa_st = wa_g + gbase + (size_t)16 * 64;
        }
        ba_a = h2f(wsb[OFF_BA + lane]);
        ba_b = h2f(wsb[OFF_BA + 64 + lane]);
    }

    float h_reg = 0.f, c_reg = 0.f, m_run = -2.0f, l_run = 0.f;
    float wt_j = 0.f, wf_j = 0.f, bt_r = 0.f;
    if (tid < HH) {
        wt_j = h2f(wsb[OFF_WT + tid]);
        wf_j = h2f(wsb[OFF_WF + tid]);
        bt_r = h2f(wsb[OFF_BT]);
    }

    const float* xrow  = x + (size_t)b * SS * II;
    const float* grow0 = GIX ? (gix + (size_t)b * SS * II) : nullptr;
    if (!is_gate && a >= 64 && a < 192) {
        const int idx = a - 64;
        float v = xrow[idx];
        sx[0][idx] = v;
        if (!GIX) {
            float vn = __shfl_down(v, 1);
            if (!(idx & 1)) s_xh_p[idx >> 1] = pack2(v, vn);
        }
    }
    if (GIX && !is_gate && a >= 192) {
        const int l = a - 192;
        sgix[0][l]      = grow0[l];
        sgix[0][64 + l] = grow0[64 + l];
    }
    __syncthreads();

    const uint4* st4 = (const uint4*)s_xh_p;
    const uint4* shp = (const uint4*)s_xh_p + 16;
    const uint4* xwp = (const uint4*)sxw_p;
    const uint4* whl = (const uint4*)whh_lds + (size_t)(wv * WHH_LC) * 64 + lane;

    for (int t = 0; t < SS; ++t) {
        const int p = t & 1;

        if (is_gate) {
            float gh = bias_h;
            #pragma unroll
            for (int c = 0; c < WHH_LC; ++c) gh = dot4(whl[c * 64], shp[c], gh);
            #pragma unroll 4
            for (int c = WHH_LC; c < 32; ++c) gh = dot4(whh_base[c * 64], shp[c], gh);
            sgh[tid] = gh;
            while (__hip_atomic_load(&flag_xw, __ATOMIC_ACQUIRE,
                                     __HIP_MEMORY_SCOPE_WORKGROUP) <= t) {}
            float gi = bias_i;
            #pragma unroll
            for (int c = 0; c < 16; ++c) gi = dot4(wreg[c], xwp[c], gi);
            sgi[tid] = gi;
        } else {
            float acc;
            if (GIX) {
                acc = 0.f;
                #pragma unroll
                for (int i = 0; i < 16; ++i) acc = dot4(wreg[i], shp[s * 16 + i], acc);
            } else {
                acc = 0.f;
                #pragma unroll
                for (int i = 0; i < 16; ++i) acc = dot4(wreg[i], st4[s * 24 + i], acc);
                #pragma unroll 4
                for (int i = 0; i < 8; ++i) acc = dot4(wa_st[i * 64], st4[s * 24 + 16 + i], acc);
            }
            sred[a] = acc;
            if (lane == 0)
                __hip_atomic_fetch_add(&flag_red, 1, __ATOMIC_ACQ_REL,
                                       __HIP_MEMORY_SCOPE_WORKGROUP);
            const int tgt = 4 * (t + 1);
            while (__hip_atomic_load(&flag_red, __ATOMIC_ACQUIRE,
                                     __HIP_MEMORY_SCOPE_WORKGROUP) < tgt) {}
            if (a < 64) {
                float s_a = sred[lane] + sred[128 + lane] + ba_a;
                float s_b = sred[64 + lane] + sred[192 + lane] + ba_b;
                if (GIX) { s_a += sgix[p][lane]; s_b += sgix[p][64 + lane]; }
                s_a = tanhf(s_a); s_b = tanhf(s_b);
                float m = fmaxf(s_a, s_b);
                for (int off = 32; off; off >>= 1) m = fmaxf(m, __shfl_xor(m, off));
                float e_a = expf(s_a - m), e_b = expf(s_b - m);
                float sum = e_a + e_b;
                for (int off = 32; off; off >>= 1) sum += __shfl_xor(sum, off);
                float inv = 1.f / sum;
                float xa = e_a * inv * sx[p][lane];
                float xb = e_b * inv * sx[p][64 + lane];
                float xa1 = __shfl_down(xa, 1), xb1 = __shfl_down(xb, 1);
                if (!(lane & 1)) {
                    sxw_p[lane >> 1]        = pack2(xa, xa1);
                    sxw_p[32 + (lane >> 1)] = pack2(xb, xb1);
                }
                if (lane == 0)
                    __hip_atomic_store(&flag_xw, t + 1, __ATOMIC_RELEASE,
                                       __HIP_MEMORY_SCOPE_WORKGROUP);
            } else if (a >= 64 && a < 192 && t + 1 < SS) {
                const int idx = a - 64;
                float v = xrow[(t + 1) * II + idx];
                sx[p ^ 1][idx] = v;
                if (!GIX) {
                    float vn = __shfl_down(v, 1);
                    if (!(idx & 1)) s_xh_p[idx >> 1] = pack2(v, vn);
                }
            } else if (GIX && a >= 192 && t + 1 < SS) {
                const float* gr = grow0 + (size_t)(t + 1) * II;
                const int l = a - 192;
                sgix[p ^ 1][l]      = gr[l];
                sgix[p ^ 1][64 + l] = gr[64 + l];
            }
        }
        __syncthreads();

        if (tid < HH) {
            const float r = 1.f / (1.f + expf(-(sgi[tid] + sgh[tid])));
            const float z = 1.f / (1.f + expf(-(sgi[tid + HH] + sgh[tid + HH])));
            const float n = tanhf(sgi[tid + 2 * HH] + r * sgh[tid + 2 * HH]);
            h_reg = (1.f - z) * n + z * h_reg;
            float hn2 = __shfl_down(h_reg, 1);
            if (!(tid & 1)) s_xh_p[64 + (tid >> 1)] = pack2(h_reg, hn2);
            float pd = wt_j * h_reg;
            for (int off = 32; off; off >>= 1) pd += __shfl_down(pd, off);
            if (lane == 0) swave[wv] = pd;
        }
        __syncthreads();

        if (tid < HH) {
            float dot = swave[0] + swave[1] + swave[2] + swave[3] + bt_r;
            float st = tanhf(dot);
            float mn = fmaxf(m_run, st);
            float aa = expf(m_run - mn), ww = expf(st - mn);
            l_run = l_run * aa + ww;
            m_run = mn;
            c_reg = c_reg * aa + ww * h_reg;
        }
    }

    __syncthreads();
    if (tid < HH) {
        float ctx = c_reg / l_run;
        float pd = wf_j * ctx;
        for (int off = 32; off; off >>= 1) pd += __shfl_down(pd, off);
        if (lane == 0) swave[wv] = pd;
    }
    __syncthreads();
    if (tid == 0) {
        float logit = swave[0] + swave[1] + swave[2] + swave[3] + h2f(wsb[OFF_BF]);
        out[b] = 1.f / (1.f + expf(-logit));
    }
}

extern "C" void kernel_launch(void* const* d_in, const int* in_sizes, int n_in,
                              void* d_out, int out_size, void* d_ws, size_t ws_size,
                              hipStream_t stream) {
    ushort_t* wsb = (ushort_t*)d_ws;
    const size_t WS_NEED = (size_t)OFF_GIX * 2 + (size_t)BB * SS * II * 4;
    const bool use_gix = ws_size >= WS_NEED;

    cvt_swz<<<dim3((128 * 48 + 255) / 256), dim3(256), 0, stream>>>(
        (const float*)d_in[1], wsb + OFF_WA, 128, 48, 384, 0);       // W_a  [128,384]
    cvt_swz<<<dim3((768 * 16 + 255) / 256), dim3(256), 0, stream>>>(
        (const float*)d_in[3], wsb + OFF_WIH, 768, 16, 128, 0);      // W_ih [768,128]
    cvt_swz<<<dim3((768 * 32 + 255) / 256), dim3(256), 0, stream>>>(
        (const float*)d_in[5], wsb + OFF_WHH, 768, 32, 256, 0);      // W_hh [768,256]
    if (use_gix) {
        cvt_swz<<<dim3((128 * 32 + 255) / 256), dim3(256), 0, stream>>>(
            (const float*)d_in[1], wsb + OFF_WAH, 128, 32, 384, 128); // W_a h-part
        cvt_swz8<<<dim3((768 * 16 + 255) / 256), dim3(256), 0, stream>>>(
            (const float*)d_in[3], wsb + OFF_WIH8, 768, 16, 128, 0);  // W_ih e5m2
    }

    struct { int src_idx; int off; int n; } cv[7] = {
        {2, OFF_BA,  II}, {4, OFF_BIH, 3 * HH}, {6, OFF_BHH, 3 * HH},
        {7, OFF_WT,  HH}, {8, OFF_BT, 1}, {9, OFF_WF, HH}, {10, OFF_BF, 1},
    };
    for (int i = 0; i < 7; ++i) {
        int blocks = (cv[i].n + 255) / 256;
        cvt_f32_f16<<<dim3(blocks), dim3(256), 0, stream>>>(
            (const float*)d_in[cv[i].src_idx], wsb + cv[i].off, cv[i].n);
    }

    float* gixf = (float*)(wsb + OFF_GIX);
    if (use_gix) {
        gix_kernel<<<dim3(BB), dim3(512), 0, stream>>>(
            (const float*)d_in[0], wsb, gixf);
        da_rnn_ws_kernel<<<dim3(BB), dim3(1024), 0, stream>>>(
            (const float*)d_in[0], wsb, gixf, (float*)d_out);
    } else {
        da_rnn_kernel<0><<<dim3(BB), dim3(1024), 0, stream>>>(
            (const float*)d_in[0], wsb, nullptr, (float*)d_out);
    }
}

// Round 12
// 2204.647 us; speedup vs baseline: 3.2769x; 2.3204x over previous
//
#include <hip/hip_runtime.h>
#include <math.h>

#define BB 256
#define SS 512
#define II 128
#define HH 256

typedef unsigned short ushort_t;
typedef unsigned int uint32;

// d_ws f16 blob element offsets (each a multiple of 8 -> 16B aligned)
#define OFF_WA   0          // 128*384 = 49152   (swizzled, 48 chunks)
#define OFF_BA   49152      // 128
#define OFF_WIH  49280      // 768*128 = 98304   (swizzled, 16 chunks)
#define OFF_BIH  147584     // 768
#define OFF_WHH  148352     // 768*256 = 196608  (swizzled, 32 chunks)
#define OFF_BHH  344960     // 768
#define OFF_WT   345728     // 256
#define OFF_BT   345984     // 1 (padded to 8)
#define OFF_WF   345992     // 256
#define OFF_BF   346248     // 1 (padded to 8)
#define OFF_WAH  346256     // 128*256 = 32768   (Wa h-part only, swizzled, 32 chunks)
#define OFF_WHH8 379024     // Whh chunks 10..31 in e5m2: 768 x 22 x 8 B = 67584 ushort units
#define OFF_GIX  446608     // fp32 [B,S,128] precomputed Wa_x . x_t

#define RES8     22   // Whh chunks 10..31: e5m2, LDS-RESIDENT (135 KB)
#define DIRF     10   // Whh chunks 0..9  : f16, streamed from L2 (R4 mechanism)
#define WHH_LC   12   // fallback kernel only

// ---------- f16 helpers ----------
__device__ __forceinline__ float h2f(ushort_t u) {
    union { ushort_t s[2]; _Float16 h[2]; } v; v.s[0] = u; return (float)v.h[0];
}
__device__ __forceinline__ ushort_t f2h(float f) {
    union { _Float16 h; ushort_t s; } v; v.h = (_Float16)f; return v.s;
}
__device__ __forceinline__ uint32 pack2(float a, float b) {
    union { _Float16 h[2]; uint32 u; } v;
    v.h[0] = (_Float16)a; v.h[1] = (_Float16)b; return v.u;
}
// f16 -> e5m2 byte (top byte of f16, RNE on the 8 dropped mantissa bits).
__device__ __forceinline__ uint32 f2e5m2(float f) {
    uint32 t = (uint32)f2h(f);
    return ((t + 0x7Fu + ((t >> 8) & 1u)) >> 8) & 0xFFu;
}

// packed-f16 dual-MAC: v_dot2_f32_f16 if available, unpack+fma fallback
#if __has_builtin(__builtin_amdgcn_fdot2)
typedef _Float16 v2h __attribute__((ext_vector_type(2)));
__device__ __forceinline__ float dot2u(uint32 w, uint32 v, float acc) {
    return __builtin_amdgcn_fdot2(
        __builtin_bit_cast(v2h, w), __builtin_bit_cast(v2h, v), acc, false);
}
#else
__device__ __forceinline__ float dot2u(uint32 w, uint32 v, float acc) {
    union { uint32 u; _Float16 h[2]; } a, b; a.u = w; b.u = v;
    acc = fmaf((float)a.h[0], (float)b.h[0], acc);
    return fmaf((float)a.h[1], (float)b.h[1], acc);
}
#endif
__device__ __forceinline__ float dot4(uint4 w, uint4 v, float acc) {
    acc = dot2u(w.x, v.x, acc); acc = dot2u(w.y, v.y, acc);
    acc = dot2u(w.z, v.z, acc); return dot2u(w.w, v.w, acc);
}

// e5m2 x4 (one uint32) -> two packed-f16 pairs via byte permute (b<<8 == f16)
#if __has_builtin(__builtin_amdgcn_perm)
__device__ __forceinline__ uint32 e5m2_lo(uint32 w) {    // bytes [0,b0,0,b1]
    return __builtin_amdgcn_perm(0u, w, 0x010c000cu);
}
__device__ __forceinline__ uint32 e5m2_hi(uint32 w) {    // bytes [0,b2,0,b3]
    return __builtin_amdgcn_perm(0u, w, 0x030c020cu);
}
#else
__device__ __forceinline__ uint32 e5m2_lo(uint32 w) {
    return ((w & 0xFFu) << 8) | ((w & 0xFF00u) << 16);
}
__device__ __forceinline__ uint32 e5m2_hi(uint32 w) {
    return ((w >> 16) & 0xFFu) << 8 | (w & 0xFF000000u);
}
#endif
// 8 e5m2 weights (uint2) . 8 f16 activations (uint4)
__device__ __forceinline__ float dot4f8(uint2 w8, uint4 v, float acc) {
    acc = dot2u(e5m2_lo(w8.x), v.x, acc);
    acc = dot2u(e5m2_hi(w8.x), v.y, acc);
    acc = dot2u(e5m2_lo(w8.y), v.z, acc);
    return dot2u(e5m2_hi(w8.y), v.w, acc);
}

__global__ void cvt_f32_f16(const float* __restrict__ src, ushort_t* __restrict__ dst, int n) {
    int i = blockIdx.x * 256 + threadIdx.x;
    if (i < n) dst[i] = f2h(src[i]);
}

// Swizzled fp32 -> f16: uint4 index = ((row/64)*chunks + c)*64 + (row%64)
__global__ void cvt_swz(const float* __restrict__ src, ushort_t* __restrict__ dst,
                        int rows, int chunks, int srcStride, int colOff) {
    int t = blockIdx.x * 256 + threadIdx.x;
    if (t >= rows * chunks) return;
    int row = t / chunks, c = t % chunks;
    const float* s = src + (size_t)row * srcStride + colOff + c * 8;
    uint4 v;
    v.x = pack2(s[0], s[1]); v.y = pack2(s[2], s[3]);
    v.z = pack2(s[4], s[5]); v.w = pack2(s[6], s[7]);
    ((uint4*)dst)[((size_t)(row >> 6) * chunks + c) * 64 + (row & 63)] = v;
}

// Swizzled fp32 -> e5m2 (8 weights -> uint2), same swizzle in uint2 units.
__global__ void cvt_swz8(const float* __restrict__ src, ushort_t* __restrict__ dst,
                         int rows, int chunks, int srcStride, int colOff) {
    int t = blockIdx.x * 256 + threadIdx.x;
    if (t >= rows * chunks) return;
    int row = t / chunks, c = t % chunks;
    const float* s = src + (size_t)row * srcStride + colOff + c * 8;
    uint2 v;
    v.x = f2e5m2(s[0]) | (f2e5m2(s[1]) << 8) | (f2e5m2(s[2]) << 16) | (f2e5m2(s[3]) << 24);
    v.y = f2e5m2(s[4]) | (f2e5m2(s[5]) << 8) | (f2e5m2(s[6]) << 16) | (f2e5m2(s[7]) << 24);
    ((uint2*)dst)[((size_t)(row >> 6) * chunks + c) * 64 + (row & 63)] = v;
}

// Pre-pass: gix[b,t,i] = dot(Wa_x[i,:], x[b,t,:])  (h-independent, hoisted).
__global__ __launch_bounds__(512, 2) void gix_kernel(
    const float* __restrict__ x, const ushort_t* __restrict__ wsb,
    float* __restrict__ gix)
{
    const int b = blockIdx.x, tid = threadIdx.x;
    const int r4 = tid >> 7, i = tid & 127;
    __shared__ __align__(16) uint32 sxp[4][64];

    uint4 w[16];
    const uint4* wa_g = (const uint4*)(wsb + OFF_WA);
    const size_t gb = (size_t)(i >> 6) * 48 * 64 + (i & 63);
    #pragma unroll
    for (int c = 0; c < 16; ++c) w[c] = wa_g[gb + (size_t)c * 64];

    const float* xb = x + (size_t)b * SS * II;
    float* gout = gix + (size_t)b * SS * II;
    for (int j = 0; j < SS; j += 4) {
        float v = xb[(j + r4) * II + i];
        float vn = __shfl_down(v, 1);
        if (!(i & 1)) sxp[r4][i >> 1] = pack2(v, vn);
        __syncthreads();
        const uint4* sx4 = (const uint4*)sxp[r4];
        float acc = 0.f;
        #pragma unroll
        for (int c = 0; c < 16; ++c) acc = dot4(w[c], sx4[c], acc);
        gout[(j + r4) * II + i] = acc;
        __syncthreads();
    }
}

// ============ main kernel: R4 structure, Whh residency in e5m2 ============
// One block (1024 threads) per batch row.
// Waves 0-11 ("gate"): thread tid owns row tid. Whh chunks 10..31 are
//   LDS-RESIDENT in e5m2 (135 KB, [chunk][row] uint2 layout) — only chunks
//   0..9 are streamed from L2 in f16. Streamed load events per step drop
//   20 -> 10 (R1's proven lever: ~285 cy exposed latency per event).
//   e5m2 quantization of Whh at this scale validated in R7 (absmax 0.0).
// Waves 12-15 ("attn"): exactly R4 — Wa_h reg-resident, wave12 softmax,
//   waves 13-14 x prefetch, wave 15 gix prefetch.
__global__ __launch_bounds__(1024, 4) void da_rnn_r12_kernel(
    const float* __restrict__ x,          // fp32 [B,S,I]
    const ushort_t* __restrict__ wsb,     // f16/e5m2 blob in d_ws
    const float* __restrict__ gix,        // fp32 [B,S,I] precomputed
    float* __restrict__ out)              // fp32 [B,1]
{
    const int b    = blockIdx.x;
    const int tid  = threadIdx.x;
    const int lane = tid & 63;
    const int wv   = tid >> 6;
    const bool is_gate = (tid < 3 * HH);

    __shared__ __align__(16) uint32 whh8_lds[RES8 * 768 * 2]; // 135 KB e5m2
    __shared__ __align__(16) uint32 s_xh_p[192];     // packed f16 [x_t(128); h(256)]
    __shared__ __align__(16) uint32 sxw_p[64];       // packed f16 alpha*x_t
    __shared__ __align__(16) float  sred[256];
    __shared__ __align__(16) float  sgi[3 * HH];
    __shared__ __align__(16) float  sgh[3 * HH];
    __shared__ __align__(16) float  sx[2][II];
    __shared__ __align__(16) float  sgix[2][II];
    __shared__ float swave[4];
    __shared__ int   flag_red;
    __shared__ int   flag_xw;

    if (tid == 0) { flag_red = 0; flag_xw = 0; }
    if (tid < II) s_xh_p[64 + tid] = 0u;             // h_0 = 0 (packed)

    // ---- role-overlaid register-resident weights (R4: one 64-VGPR array) ----
    uint4 wreg[16];
    const int a   = tid - 3 * HH;
    const int row = a & 127;
    const int s   = a >> 7;
    const uint4* whh_base = (const uint4*)(wsb + OFF_WHH) + (size_t)wv * 32 * 64 + lane;
    float bias_i = 0.f, bias_h = 0.f, ba_a = 0.f, ba_b = 0.f;

    if (is_gate) {
        const uint4* wih_g = (const uint4*)(wsb + OFF_WIH) + (size_t)wv * 16 * 64 + lane;
        #pragma unroll
        for (int c = 0; c < 16; ++c) wreg[c] = wih_g[c * 64];
        bias_i = h2f(wsb[OFF_BIH + tid]);
        bias_h = h2f(wsb[OFF_BHH + tid]);
        // fill e5m2 Whh residency: thread tid owns row tid, 22 chunks
        {
            const uint2* g8 = (const uint2*)(wsb + OFF_WHH8);
            const size_t gb8 = (size_t)(tid >> 6) * RES8 * 64 + (tid & 63);
            uint2* l8 = (uint2*)whh8_lds;
            #pragma unroll
            for (int c = 0; c < RES8; ++c)
                l8[c * 768 + tid] = g8[gb8 + (size_t)c * 64];
        }
    } else {
        const uint4* wah_g = (const uint4*)(wsb + OFF_WAH);
        const size_t gbh = ((size_t)(row >> 6) * 32 + s * 16) * 64 + (row & 63);
        #pragma unroll
        for (int i = 0; i < 16; ++i) wreg[i] = wah_g[gbh + (size_t)i * 64];
        ba_a = h2f(wsb[OFF_BA + lane]);
        ba_b = h2f(wsb[OFF_BA + 64 + lane]);
    }

    float h_reg = 0.f, c_reg = 0.f, m_run = -2.0f, l_run = 0.f;
    float wt_j = 0.f, wf_j = 0.f, bt_r = 0.f;
    if (tid < HH) {
        wt_j = h2f(wsb[OFF_WT + tid]);
        wf_j = h2f(wsb[OFF_WF + tid]);
        bt_r = h2f(wsb[OFF_BT]);
    }

    const float* xrow  = x   + (size_t)b * SS * II;
    const float* grow0 = gix + (size_t)b * SS * II;
    if (!is_gate && a >= 64 && a < 192) {            // x_0 load
        const int idx = a - 64;
        sx[0][idx] = xrow[idx];
    }
    if (!is_gate && a >= 192) {                      // gix_0 load
        const int l = a - 192;
        sgix[0][l]      = grow0[l];
        sgix[0][64 + l] = grow0[64 + l];
    }
    __syncthreads();                                  // residency + h0/x0 visible

    const uint4* shp = (const uint4*)s_xh_p + 16;    // 32 chunks of h
    const uint4* xwp = (const uint4*)sxw_p;          // 16 chunks of xw
    const uint2* w8l = (const uint2*)whh8_lds + tid; // per-row e5m2 read ptr

    for (int t = 0; t < SS; ++t) {
        const int p = t & 1;

        if (is_gate) {
            // gh = Whh . h_t : 22 e5m2 LDS-resident dots + 10 streamed f16.
            float gh = bias_h;
            #pragma unroll
            for (int c = 0; c < RES8; ++c)
                gh = dot4f8(w8l[c * 768], shp[DIRF + c], gh);
            #pragma unroll 5
            for (int c = 0; c < DIRF; ++c)
                gh = dot4(whh_base[c * 64], shp[c], gh);
            sgh[tid] = gh;
            // wait for xw, then reg-resident Wih dot (R4)
            while (__hip_atomic_load(&flag_xw, __ATOMIC_ACQUIRE,
                                     __HIP_MEMORY_SCOPE_WORKGROUP) <= t) {}
            float gi = bias_i;
            #pragma unroll
            for (int c = 0; c < 16; ++c) gi = dot4(wreg[c], xwp[c], gi);
            sgi[tid] = gi;
        } else {
            // Wa_h score partials (reg-resident)
            float acc = 0.f;
            #pragma unroll
            for (int i = 0; i < 16; ++i) acc = dot4(wreg[i], shp[s * 16 + i], acc);
            sred[a] = acc;
            if (lane == 0)
                __hip_atomic_fetch_add(&flag_red, 1, __ATOMIC_ACQ_REL,
                                       __HIP_MEMORY_SCOPE_WORKGROUP);
            const int tgt = 4 * (t + 1);
            while (__hip_atomic_load(&flag_red, __ATOMIC_ACQUIRE,
                                     __HIP_MEMORY_SCOPE_WORKGROUP) < tgt) {}
            if (a < 64) {
                // wave 12: combine + tanh + softmax + packed xw
                float s_a = sred[lane] + sred[128 + lane] + sgix[p][lane] + ba_a;
                float s_b = sred[64 + lane] + sred[192 + lane] + sgix[p][64 + lane] + ba_b;
                s_a = tanhf(s_a); s_b = tanhf(s_b);
                float m = fmaxf(s_a, s_b);
                for (int off = 32; off; off >>= 1) m = fmaxf(m, __shfl_xor(m, off));
                float e_a = expf(s_a - m), e_b = expf(s_b - m);
                float sum = e_a + e_b;
                for (int off = 32; off; off >>= 1) sum += __shfl_xor(sum, off);
                float inv = 1.f / sum;
                float xa = e_a * inv * sx[p][lane];
                float xb = e_b * inv * sx[p][64 + lane];
                float xa1 = __shfl_down(xa, 1), xb1 = __shfl_down(xb, 1);
                if (!(lane & 1)) {
                    sxw_p[lane >> 1]        = pack2(xa, xa1);
                    sxw_p[32 + (lane >> 1)] = pack2(xb, xb1);
                }
                if (lane == 0)
                    __hip_atomic_store(&flag_xw, t + 1, __ATOMIC_RELEASE,
                                       __HIP_MEMORY_SCOPE_WORKGROUP);
            } else if (a >= 64 && a < 192 && t + 1 < SS) {
                // waves 13-14: prefetch x_{t+1}
                const int idx = a - 64;
                sx[p ^ 1][idx] = xrow[(t + 1) * II + idx];
            } else if (a >= 192 && t + 1 < SS) {
                // wave 15: prefetch gix_{t+1}
                const float* gr = grow0 + (size_t)(t + 1) * II;
                const int l = a - 192;
                sgix[p ^ 1][l]      = gr[l];
                sgix[p ^ 1][64 + l] = gr[64 + l];
            }
        }
        __syncthreads();                              // B1: gates done, x prefetched

        if (tid < HH) {
            const float r = 1.f / (1.f + expf(-(sgi[tid] + sgh[tid])));
            const float z = 1.f / (1.f + expf(-(sgi[tid + HH] + sgh[tid + HH])));
            const float n = tanhf(sgi[tid + 2 * HH] + r * sgh[tid + 2 * HH]);
            h_reg = (1.f - z) * n + z * h_reg;
            float hn2 = __shfl_down(h_reg, 1);
            if (!(tid & 1)) s_xh_p[64 + (tid >> 1)] = pack2(h_reg, hn2);
            float pd = wt_j * h_reg;
            for (int off = 32; off; off >>= 1) pd += __shfl_down(pd, off);
            if (lane == 0) swave[wv] = pd;
        }
        __syncthreads();                              // B2: h ready (loop barrier)

        if (tid < HH) {
            // redundant per-thread online softmax over time (no extra barrier)
            float dot = swave[0] + swave[1] + swave[2] + swave[3] + bt_r;
            float st = tanhf(dot);
            float mn = fmaxf(m_run, st);
            float aa = expf(m_run - mn), ww = expf(st - mn);
            l_run = l_run * aa + ww;
            m_run = mn;
            c_reg = c_reg * aa + ww * h_reg;
        }
    }

    __syncthreads();
    if (tid < HH) {
        float ctx = c_reg / l_run;
        float pd = wf_j * ctx;
        for (int off = 32; off; off >>= 1) pd += __shfl_down(pd, off);
        if (lane == 0) swave[wv] = pd;
    }
    __syncthreads();
    if (tid == 0) {
        float logit = swave[0] + swave[1] + swave[2] + swave[3] + h2f(wsb[OFF_BF]);
        out[b] = 1.f / (1.f + expf(-logit));
    }
}

// ============ single-row fallback (R4 structure, GIX=0 path) ============
template <int GIX>
__global__ __launch_bounds__(1024, 4) void da_rnn_kernel(
    const float* __restrict__ x, const ushort_t* __restrict__ wsb,
    const float* __restrict__ gix, float* __restrict__ out)
{
    const int b    = blockIdx.x;
    const int tid  = threadIdx.x;
    const int lane = tid & 63;
    const int wv   = tid >> 6;
    const bool is_gate = (tid < 3 * HH);

    __shared__ __align__(16) uint32 whh_lds[WHH_LC * 768 * 4];
    __shared__ __align__(16) uint32 s_xh_p[192];
    __shared__ __align__(16) uint32 sxw_p[64];
    __shared__ __align__(16) float  sred[256];
    __shared__ __align__(16) float  sgi[3 * HH];
    __shared__ __align__(16) float  sgh[3 * HH];
    __shared__ __align__(16) float  sx[2][II];
    __shared__ __align__(16) float  sgix[2][II];
    __shared__ float swave[4];
    __shared__ int   flag_red;
    __shared__ int   flag_xw;

    if (tid == 0) { flag_red = 0; flag_xw = 0; }
    if (tid < II) s_xh_p[64 + tid] = 0u;

    uint4 wreg[16];
    const int a   = tid - 3 * HH;
    const int row = a & 127;
    const int s   = a >> 7;
    const uint4* whh_base = (const uint4*)(wsb + OFF_WHH) + (size_t)wv * 32 * 64 + lane;
    const uint4* wa_st = nullptr;
    float bias_i = 0.f, bias_h = 0.f, ba_a = 0.f, ba_b = 0.f;

    if (is_gate) {
        const uint4* wih_g = (const uint4*)(wsb + OFF_WIH) + (size_t)wv * 16 * 64 + lane;
        #pragma unroll
        for (int c = 0; c < 16; ++c) wreg[c] = wih_g[c * 64];
        bias_i = h2f(wsb[OFF_BIH + tid]);
        bias_h = h2f(wsb[OFF_BHH + tid]);
        #pragma unroll
        for (int c = 0; c < WHH_LC; ++c)
            ((uint4*)whh_lds)[(wv * WHH_LC + c) * 64 + lane] = whh_base[c * 64];
    } else {
        if (GIX) {
            const uint4* wah_g = (const uint4*)(wsb + OFF_WAH);
            const size_t gbh = ((size_t)(row >> 6) * 32 + s * 16) * 64 + (row & 63);
            #pragma unroll
            for (int i = 0; i < 16; ++i) wreg[i] = wah_g[gbh + (size_t)i * 64];
        } else {
            const uint4* wa_g = (const uint4*)(wsb + OFF_WA);
            const size_t gbase = ((size_t)(row >> 6) * 48 + s * 24) * 64 + (row & 63);
            #pragma unroll
            for (int i = 0; i < 16; ++i) wreg[i] = wa_g[gbase + (size_t)i * 64];
            wa_st = wa_g + gbase + (size_t)16 * 64;
        }
        ba_a = h2f(wsb[OFF_BA + lane]);
        ba_b = h2f(wsb[OFF_BA + 64 + lane]);
    }

    float h_reg = 0.f, c_reg = 0.f, m_run = -2.0f, l_run = 0.f;
    float wt_j = 0.f, wf_j = 0.f, bt_r = 0.f;
    if (tid < HH) {
        wt_j = h2f(wsb[OFF_WT + tid]);
        wf_j = h2f(wsb[OFF_WF + tid]);
        bt_r = h2f(wsb[OFF_BT]);
    }

    const float* xrow  = x + (size_t)b * SS * II;
    const float* grow0 = GIX ? (gix + (size_t)b * SS * II) : nullptr;
    if (!is_gate && a >= 64 && a < 192) {
        const int idx = a - 64;
        float v = xrow[idx];
        sx[0][idx] = v;
        if (!GIX) {
            float vn = __shfl_down(v, 1);
            if (!(idx & 1)) s_xh_p[idx >> 1] = pack2(v, vn);
        }
    }
    if (GIX && !is_gate && a >= 192) {
        const int l = a - 192;
        sgix[0][l]      = grow0[l];
        sgix[0][64 + l] = grow0[64 + l];
    }
    __syncthreads();

    const uint4* st4 = (const uint4*)s_xh_p;
    const uint4* shp = (const uint4*)s_xh_p + 16;
    const uint4* xwp = (const uint4*)sxw_p;
    const uint4* whl = (const uint4*)whh_lds + (size_t)(wv * WHH_LC) * 64 + lane;

    for (int t = 0; t < SS; ++t) {
        const int p = t & 1;

        if (is_gate) {
            float gh = bias_h;
            #pragma unroll
            for (int c = 0; c < WHH_LC; ++c) gh = dot4(whl[c * 64], shp[c], gh);
            #pragma unroll 4
            for (int c = WHH_LC; c < 32; ++c) gh = dot4(whh_base[c * 64], shp[c], gh);
            sgh[tid] = gh;
            while (__hip_atomic_load(&flag_xw, __ATOMIC_ACQUIRE,
                                     __HIP_MEMORY_SCOPE_WORKGROUP) <= t) {}
            float gi = bias_i;
            #pragma unroll
            for (int c = 0; c < 16; ++c) gi = dot4(wreg[c], xwp[c], gi);
            sgi[tid] = gi;
        } else {
            float acc;
            if (GIX) {
                acc = 0.f;
                #pragma unroll
                for (int i = 0; i < 16; ++i) acc = dot4(wreg[i], shp[s * 16 + i], acc);
            } else {
                acc = 0.f;
                #pragma unroll
                for (int i = 0; i < 16; ++i) acc = dot4(wreg[i], st4[s * 24 + i], acc);
                #pragma unroll 4
                for (int i = 0; i < 8; ++i) acc = dot4(wa_st[i * 64], st4[s * 24 + 16 + i], acc);
            }
            sred[a] = acc;
            if (lane == 0)
                __hip_atomic_fetch_add(&flag_red, 1, __ATOMIC_ACQ_REL,
                                       __HIP_MEMORY_SCOPE_WORKGROUP);
            const int tgt = 4 * (t + 1);
            while (__hip_atomic_load(&flag_red, __ATOMIC_ACQUIRE,
                                     __HIP_MEMORY_SCOPE_WORKGROUP) < tgt) {}
            if (a < 64) {
                float s_a = sred[lane] + sred[128 + lane] + ba_a;
                float s_b = sred[64 + lane] + sred[192 + lane] + ba_b;
                if (GIX) { s_a += sgix[p][lane]; s_b += sgix[p][64 + lane]; }
                s_a = tanhf(s_a); s_b = tanhf(s_b);
                float m = fmaxf(s_a, s_b);
                for (int off = 32; off; off >>= 1) m = fmaxf(m, __shfl_xor(m, off));
                float e_a = expf(s_a - m), e_b = expf(s_b - m);
                float sum = e_a + e_b;
                for (int off = 32; off; off >>= 1) sum += __shfl_xor(sum, off);
                float inv = 1.f / sum;
                float xa = e_a * inv * sx[p][lane];
                float xb = e_b * inv * sx[p][64 + lane];
                float xa1 = __shfl_down(xa, 1), xb1 = __shfl_down(xb, 1);
                if (!(lane & 1)) {
                    sxw_p[lane >> 1]        = pack2(xa, xa1);
                    sxw_p[32 + (lane >> 1)] = pack2(xb, xb1);
                }
                if (lane == 0)
                    __hip_atomic_store(&flag_xw, t + 1, __ATOMIC_RELEASE,
                                       __HIP_MEMORY_SCOPE_WORKGROUP);
            } else if (a >= 64 && a < 192 && t + 1 < SS) {
                const int idx = a - 64;
                float v = xrow[(t + 1) * II + idx];
                sx[p ^ 1][idx] = v;
                if (!GIX) {
                    float vn = __shfl_down(v, 1);
                    if (!(idx & 1)) s_xh_p[idx >> 1] = pack2(v, vn);
                }
            } else if (GIX && a >= 192 && t + 1 < SS) {
                const float* gr = grow0 + (size_t)(t + 1) * II;
                const int l = a - 192;
                sgix[p ^ 1][l]      = gr[l];
                sgix[p ^ 1][64 + l] = gr[64 + l];
            }
        }
        __syncthreads();

        if (tid < HH) {
            const float r = 1.f / (1.f + expf(-(sgi[tid] + sgh[tid])));
            const float z = 1.f / (1.f + expf(-(sgi[tid + HH] + sgh[tid + HH])));
            const float n = tanhf(sgi[tid + 2 * HH] + r * sgh[tid + 2 * HH]);
            h_reg = (1.f - z) * n + z * h_reg;
            float hn2 = __shfl_down(h_reg, 1);
            if (!(tid & 1)) s_xh_p[64 + (tid >> 1)] = pack2(h_reg, hn2);
            float pd = wt_j * h_reg;
            for (int off = 32; off; off >>= 1) pd += __shfl_down(pd, off);
            if (lane == 0) swave[wv] = pd;
        }
        __syncthreads();

        if (tid < HH) {
            float dot = swave[0] + swave[1] + swave[2] + swave[3] + bt_r;
            float st = tanhf(dot);
            float mn = fmaxf(m_run, st);
            float aa = expf(m_run - mn), ww = expf(st - mn);
            l_run = l_run * aa + ww;
            m_run = mn;
            c_reg = c_reg * aa + ww * h_reg;
        }
    }

    __syncthreads();
    if (tid < HH) {
        float ctx = c_reg / l_run;
        float pd = wf_j * ctx;
        for (int off = 32; off; off >>= 1) pd += __shfl_down(pd, off);
        if (lane == 0) swave[wv] = pd;
    }
    __syncthreads();
    if (tid == 0) {
        float logit = swave[0] + swave[1] + swave[2] + swave[3] + h2f(wsb[OFF_BF]);
        out[b] = 1.f / (1.f + expf(-logit));
    }
}

extern "C" void kernel_launch(void* const* d_in, const int* in_sizes, int n_in,
                              void* d_out, int out_size, void* d_ws, size_t ws_size,
                              hipStream_t stream) {
    ushort_t* wsb = (ushort_t*)d_ws;
    const size_t WS_NEED = (size_t)OFF_GIX * 2 + (size_t)BB * SS * II * 4;
    const bool use_gix = ws_size >= WS_NEED;

    cvt_swz<<<dim3((128 * 48 + 255) / 256), dim3(256), 0, stream>>>(
        (const float*)d_in[1], wsb + OFF_WA, 128, 48, 384, 0);       // W_a  [128,384]
    cvt_swz<<<dim3((768 * 16 + 255) / 256), dim3(256), 0, stream>>>(
        (const float*)d_in[3], wsb + OFF_WIH, 768, 16, 128, 0);      // W_ih [768,128]
    cvt_swz<<<dim3((768 * 32 + 255) / 256), dim3(256), 0, stream>>>(
        (const float*)d_in[5], wsb + OFF_WHH, 768, 32, 256, 0);      // W_hh [768,256]
    if (use_gix) {
        cvt_swz<<<dim3((128 * 32 + 255) / 256), dim3(256), 0, stream>>>(
            (const float*)d_in[1], wsb + OFF_WAH, 128, 32, 384, 128); // W_a h-part
        cvt_swz8<<<dim3((768 * RES8 + 255) / 256), dim3(256), 0, stream>>>(
            (const float*)d_in[5], wsb + OFF_WHH8, 768, RES8, 256, DIRF * 8); // Whh e5m2 ch10..31
    }

    struct { int src_idx; int off; int n; } cv[7] = {
        {2, OFF_BA,  II}, {4, OFF_BIH, 3 * HH}, {6, OFF_BHH, 3 * HH},
        {7, OFF_WT,  HH}, {8, OFF_BT, 1}, {9, OFF_WF, HH}, {10, OFF_BF, 1},
    };
    for (int i = 0; i < 7; ++i) {
        int blocks = (cv[i].n + 255) / 256;
        cvt_f32_f16<<<dim3(blocks), dim3(256), 0, stream>>>(
            (const float*)d_in[cv[i].src_idx], wsb + cv[i].off, cv[i].n);
    }

    float* gixf = (float*)(wsb + OFF_GIX);
    if (use_gix) {
        gix_kernel<<<dim3(BB), dim3(512), 0, stream>>>(
            (const float*)d_in[0], wsb, gixf);
        da_rnn_r12_kernel<<<dim3(BB), dim3(1024), 0, stream>>>(
            (const float*)d_in[0], wsb, gixf, (float*)d_out);
    } else {
        da_rnn_kernel<0><<<dim3(BB), dim3(1024), 0, stream>>>(
            (const float*)d_in[0], wsb, nullptr, (float*)d_out);
    }
}

// Round 13
// 2011.631 us; speedup vs baseline: 3.5914x; 1.0960x over previous
//
#include <hip/hip_runtime.h>
#include <math.h>

#define BB 256
#define SS 512
#define II 128
#define HH 256

typedef unsigned short ushort_t;
typedef unsigned int uint32;

// d_ws f16 blob element offsets (each a multiple of 8 -> 16B aligned)
#define OFF_WA   0          // 128*384 = 49152   (swizzled, 48 chunks)
#define OFF_BA   49152      // 128
#define OFF_WIH  49280      // 768*128 = 98304   (swizzled, 16 chunks)
#define OFF_BIH  147584     // 768
#define OFF_WHH  148352     // 768*256 = 196608  (swizzled, 32 chunks)
#define OFF_BHH  344960     // 768
#define OFF_WT   345728     // 256
#define OFF_BT   345984     // 1 (padded to 8)
#define OFF_WF   345992     // 256
#define OFF_BF   346248     // 1 (padded to 8)
#define OFF_WAH  346256     // 128*256 = 32768   (Wa h-part only, swizzled, 32 chunks)
#define OFF_WHH8 379024     // Whh chunks 8..31 in e5m2: 768 x 24 x 8 B = 73728 ushort units
#define OFF_GIX  452752     // fp32 [B,S,128] precomputed Wa_x . x_t

#define RES8     24   // Whh chunks 8..31: e5m2, LDS-RESIDENT (147.5 KB)
#define DIRF     8    // Whh chunks 0..7 : f16, streamed from L2
#define WHH_LC   12   // fallback kernel only

// ---------- f16 helpers ----------
__device__ __forceinline__ float h2f(ushort_t u) {
    union { ushort_t s[2]; _Float16 h[2]; } v; v.s[0] = u; return (float)v.h[0];
}
__device__ __forceinline__ ushort_t f2h(float f) {
    union { _Float16 h; ushort_t s; } v; v.h = (_Float16)f; return v.s;
}
__device__ __forceinline__ uint32 pack2(float a, float b) {
    union { _Float16 h[2]; uint32 u; } v;
    v.h[0] = (_Float16)a; v.h[1] = (_Float16)b; return v.u;
}
// f16 -> e5m2 byte (top byte of f16, RNE on the 8 dropped mantissa bits).
__device__ __forceinline__ uint32 f2e5m2(float f) {
    uint32 t = (uint32)f2h(f);
    return ((t + 0x7Fu + ((t >> 8) & 1u)) >> 8) & 0xFFu;
}

// ---------- fast transcendentals (v_exp_f32 / v_rcp_f32 based) ----------
// rel-err ~1e-6 — far inside this kernel's e5m2-validated tolerance.
__device__ __forceinline__ float frcp(float x) { return __builtin_amdgcn_rcpf(x); }
__device__ __forceinline__ float fexp(float x) { return __expf(x); }
__device__ __forceinline__ float fsig(float x) {
    return frcp(1.f + __expf(-x));
}
__device__ __forceinline__ float ftanh(float x) {
    float e = __expf(2.f * x);
    return (e - 1.f) * frcp(e + 1.f);
}

// packed-f16 dual-MAC: v_dot2_f32_f16 if available, unpack+fma fallback
#if __has_builtin(__builtin_amdgcn_fdot2)
typedef _Float16 v2h __attribute__((ext_vector_type(2)));
__device__ __forceinline__ float dot2u(uint32 w, uint32 v, float acc) {
    return __builtin_amdgcn_fdot2(
        __builtin_bit_cast(v2h, w), __builtin_bit_cast(v2h, v), acc, false);
}
#else
__device__ __forceinline__ float dot2u(uint32 w, uint32 v, float acc) {
    union { uint32 u; _Float16 h[2]; } a, b; a.u = w; b.u = v;
    acc = fmaf((float)a.h[0], (float)b.h[0], acc);
    return fmaf((float)a.h[1], (float)b.h[1], acc);
}
#endif
__device__ __forceinline__ float dot4(uint4 w, uint4 v, float acc) {
    acc = dot2u(w.x, v.x, acc); acc = dot2u(w.y, v.y, acc);
    acc = dot2u(w.z, v.z, acc); return dot2u(w.w, v.w, acc);
}

// e5m2 x4 (one uint32) -> two packed-f16 pairs via byte permute (b<<8 == f16)
#if __has_builtin(__builtin_amdgcn_perm)
__device__ __forceinline__ uint32 e5m2_lo(uint32 w) {    // bytes [0,b0,0,b1]
    return __builtin_amdgcn_perm(0u, w, 0x010c000cu);
}
__device__ __forceinline__ uint32 e5m2_hi(uint32 w) {    // bytes [0,b2,0,b3]
    return __builtin_amdgcn_perm(0u, w, 0x030c020cu);
}
#else
__device__ __forceinline__ uint32 e5m2_lo(uint32 w) {
    return ((w & 0xFFu) << 8) | ((w & 0xFF00u) << 16);
}
__device__ __forceinline__ uint32 e5m2_hi(uint32 w) {
    return ((w >> 16) & 0xFFu) << 8 | (w & 0xFF000000u);
}
#endif
// 8 e5m2 weights (uint2) . 8 f16 activations (uint4)
__device__ __forceinline__ float dot4f8(uint2 w8, uint4 v, float acc) {
    acc = dot2u(e5m2_lo(w8.x), v.x, acc);
    acc = dot2u(e5m2_hi(w8.x), v.y, acc);
    acc = dot2u(e5m2_lo(w8.y), v.z, acc);
    return dot2u(e5m2_hi(w8.y), v.w, acc);
}

__global__ void cvt_f32_f16(const float* __restrict__ src, ushort_t* __restrict__ dst, int n) {
    int i = blockIdx.x * 256 + threadIdx.x;
    if (i < n) dst[i] = f2h(src[i]);
}

// Swizzled fp32 -> f16: uint4 index = ((row/64)*chunks + c)*64 + (row%64)
__global__ void cvt_swz(const float* __restrict__ src, ushort_t* __restrict__ dst,
                        int rows, int chunks, int srcStride, int colOff) {
    int t = blockIdx.x * 256 + threadIdx.x;
    if (t >= rows * chunks) return;
    int row = t / chunks, c = t % chunks;
    const float* s = src + (size_t)row * srcStride + colOff + c * 8;
    uint4 v;
    v.x = pack2(s[0], s[1]); v.y = pack2(s[2], s[3]);
    v.z = pack2(s[4], s[5]); v.w = pack2(s[6], s[7]);
    ((uint4*)dst)[((size_t)(row >> 6) * chunks + c) * 64 + (row & 63)] = v;
}

// Swizzled fp32 -> e5m2 (8 weights -> uint2), same swizzle in uint2 units.
__global__ void cvt_swz8(const float* __restrict__ src, ushort_t* __restrict__ dst,
                         int rows, int chunks, int srcStride, int colOff) {
    int t = blockIdx.x * 256 + threadIdx.x;
    if (t >= rows * chunks) return;
    int row = t / chunks, c = t % chunks;
    const float* s = src + (size_t)row * srcStride + colOff + c * 8;
    uint2 v;
    v.x = f2e5m2(s[0]) | (f2e5m2(s[1]) << 8) | (f2e5m2(s[2]) << 16) | (f2e5m2(s[3]) << 24);
    v.y = f2e5m2(s[4]) | (f2e5m2(s[5]) << 8) | (f2e5m2(s[6]) << 16) | (f2e5m2(s[7]) << 24);
    ((uint2*)dst)[((size_t)(row >> 6) * chunks + c) * 64 + (row & 63)] = v;
}

// Pre-pass: gix[b,t,i] = dot(Wa_x[i,:], x[b,t,:])  (h-independent, hoisted).
__global__ __launch_bounds__(512, 2) void gix_kernel(
    const float* __restrict__ x, const ushort_t* __restrict__ wsb,
    float* __restrict__ gix)
{
    const int b = blockIdx.x, tid = threadIdx.x;
    const int r4 = tid >> 7, i = tid & 127;
    __shared__ __align__(16) uint32 sxp[4][64];

    uint4 w[16];
    const uint4* wa_g = (const uint4*)(wsb + OFF_WA);
    const size_t gb = (size_t)(i >> 6) * 48 * 64 + (i & 63);
    #pragma unroll
    for (int c = 0; c < 16; ++c) w[c] = wa_g[gb + (size_t)c * 64];

    const float* xb = x + (size_t)b * SS * II;
    float* gout = gix + (size_t)b * SS * II;
    for (int j = 0; j < SS; j += 4) {
        float v = xb[(j + r4) * II + i];
        float vn = __shfl_down(v, 1);
        if (!(i & 1)) sxp[r4][i >> 1] = pack2(v, vn);
        __syncthreads();
        const uint4* sx4 = (const uint4*)sxp[r4];
        float acc = 0.f;
        #pragma unroll
        for (int c = 0; c < 16; ++c) acc = dot4(w[c], sx4[c], acc);
        gout[(j + r4) * II + i] = acc;
        __syncthreads();
    }
}

// ============ main kernel: R12 structure, RES8=24 + fast transcendentals ============
// One block (1024 threads) per batch row.
// Waves 0-11 ("gate"): thread tid owns row tid. Whh chunks 8..31 LDS-RESIDENT
//   in e5m2 (147.5 KB); only chunks 0..7 streamed from L2 in f16 (8 events/step,
//   down from R4's 20 — R12 measured −0.37 us/step for the first 10 removed).
// All transcendentals on the serial h->scores->softmax->xw->gi->h' spine use
//   v_exp_f32/v_rcp_f32 forms (~4 instr vs ~25 libm) — rel-err ~1e-6.
// Waves 12-15 ("attn"): Wa_h reg-resident, wave12 softmax, waves 13-14
//   x prefetch, wave 15 gix prefetch.
__global__ __launch_bounds__(1024, 4) void da_rnn_r13_kernel(
    const float* __restrict__ x,          // fp32 [B,S,I]
    const ushort_t* __restrict__ wsb,     // f16/e5m2 blob in d_ws
    const float* __restrict__ gix,        // fp32 [B,S,I] precomputed
    float* __restrict__ out)              // fp32 [B,1]
{
    const int b    = blockIdx.x;
    const int tid  = threadIdx.x;
    const int lane = tid & 63;
    const int wv   = tid >> 6;
    const bool is_gate = (tid < 3 * HH);

    __shared__ __align__(16) uint32 whh8_lds[RES8 * 768 * 2]; // 147.5 KB e5m2
    __shared__ __align__(16) uint32 s_xh_p[192];     // packed f16 [x_t(128); h(256)]
    __shared__ __align__(16) uint32 sxw_p[64];       // packed f16 alpha*x_t
    __shared__ __align__(16) float  sred[256];
    __shared__ __align__(16) float  sgi[3 * HH];
    __shared__ __align__(16) float  sgh[3 * HH];
    __shared__ __align__(16) float  sx[2][II];
    __shared__ __align__(16) float  sgix[2][II];
    __shared__ float swave[4];
    __shared__ int   flag_red;
    __shared__ int   flag_xw;

    if (tid == 0) { flag_red = 0; flag_xw = 0; }
    if (tid < II) s_xh_p[64 + tid] = 0u;             // h_0 = 0 (packed)

    // ---- role-overlaid register-resident weights (R4: one 64-VGPR array) ----
    uint4 wreg[16];
    const int a   = tid - 3 * HH;
    const int row = a & 127;
    const int s   = a >> 7;
    const uint4* whh_base = (const uint4*)(wsb + OFF_WHH) + (size_t)wv * 32 * 64 + lane;
    float bias_i = 0.f, bias_h = 0.f, ba_a = 0.f, ba_b = 0.f;

    if (is_gate) {
        const uint4* wih_g = (const uint4*)(wsb + OFF_WIH) + (size_t)wv * 16 * 64 + lane;
        #pragma unroll
        for (int c = 0; c < 16; ++c) wreg[c] = wih_g[c * 64];
        bias_i = h2f(wsb[OFF_BIH + tid]);
        bias_h = h2f(wsb[OFF_BHH + tid]);
        // fill e5m2 Whh residency: thread tid owns row tid, 24 chunks
        {
            const uint2* g8 = (const uint2*)(wsb + OFF_WHH8);
            const size_t gb8 = (size_t)(tid >> 6) * RES8 * 64 + (tid & 63);
            uint2* l8 = (uint2*)whh8_lds;
            #pragma unroll
            for (int c = 0; c < RES8; ++c)
                l8[c * 768 + tid] = g8[gb8 + (size_t)c * 64];
        }
    } else {
        const uint4* wah_g = (const uint4*)(wsb + OFF_WAH);
        const size_t gbh = ((size_t)(row >> 6) * 32 + s * 16) * 64 + (row & 63);
        #pragma unroll
        for (int i = 0; i < 16; ++i) wreg[i] = wah_g[gbh + (size_t)i * 64];
        ba_a = h2f(wsb[OFF_BA + lane]);
        ba_b = h2f(wsb[OFF_BA + 64 + lane]);
    }

    float h_reg = 0.f, c_reg = 0.f, m_run = -2.0f, l_run = 0.f;
    float wt_j = 0.f, wf_j = 0.f, bt_r = 0.f;
    if (tid < HH) {
        wt_j = h2f(wsb[OFF_WT + tid]);
        wf_j = h2f(wsb[OFF_WF + tid]);
        bt_r = h2f(wsb[OFF_BT]);
    }

    const float* xrow  = x   + (size_t)b * SS * II;
    const float* grow0 = gix + (size_t)b * SS * II;
    if (!is_gate && a >= 64 && a < 192) {            // x_0 load
        const int idx = a - 64;
        sx[0][idx] = xrow[idx];
    }
    if (!is_gate && a >= 192) {                      // gix_0 load
        const int l = a - 192;
        sgix[0][l]      = grow0[l];
        sgix[0][64 + l] = grow0[64 + l];
    }
    __syncthreads();                                  // residency + h0/x0 visible

    const uint4* shp = (const uint4*)s_xh_p + 16;    // 32 chunks of h
    const uint4* xwp = (const uint4*)sxw_p;          // 16 chunks of xw
    const uint2* w8l = (const uint2*)whh8_lds + tid; // per-row e5m2 read ptr

    for (int t = 0; t < SS; ++t) {
        const int p = t & 1;

        if (is_gate) {
            // gh = Whh . h_t : 24 e5m2 LDS-resident dots + 8 streamed f16.
            float gh = bias_h;
            #pragma unroll
            for (int c = 0; c < RES8; ++c)
                gh = dot4f8(w8l[c * 768], shp[DIRF + c], gh);
            #pragma unroll 4
            for (int c = 0; c < DIRF; ++c)
                gh = dot4(whh_base[c * 64], shp[c], gh);
            sgh[tid] = gh;
            // wait for xw, then reg-resident Wih dot
            while (__hip_atomic_load(&flag_xw, __ATOMIC_ACQUIRE,
                                     __HIP_MEMORY_SCOPE_WORKGROUP) <= t) {}
            float gi = bias_i;
            #pragma unroll
            for (int c = 0; c < 16; ++c) gi = dot4(wreg[c], xwp[c], gi);
            sgi[tid] = gi;
        } else {
            // Wa_h score partials (reg-resident)
            float acc = 0.f;
            #pragma unroll
            for (int i = 0; i < 16; ++i) acc = dot4(wreg[i], shp[s * 16 + i], acc);
            sred[a] = acc;
            if (lane == 0)
                __hip_atomic_fetch_add(&flag_red, 1, __ATOMIC_ACQ_REL,
                                       __HIP_MEMORY_SCOPE_WORKGROUP);
            const int tgt = 4 * (t + 1);
            while (__hip_atomic_load(&flag_red, __ATOMIC_ACQUIRE,
                                     __HIP_MEMORY_SCOPE_WORKGROUP) < tgt) {}
            if (a < 64) {
                // wave 12: combine + tanh + softmax + packed xw (fast paths)
                float s_a = sred[lane] + sred[128 + lane] + sgix[p][lane] + ba_a;
                float s_b = sred[64 + lane] + sred[192 + lane] + sgix[p][64 + lane] + ba_b;
                s_a = ftanh(s_a); s_b = ftanh(s_b);
                float m = fmaxf(s_a, s_b);
                for (int off = 32; off; off >>= 1) m = fmaxf(m, __shfl_xor(m, off));
                float e_a = fexp(s_a - m), e_b = fexp(s_b - m);
                float sum = e_a + e_b;
                for (int off = 32; off; off >>= 1) sum += __shfl_xor(sum, off);
                float inv = frcp(sum);
                float xa = e_a * inv * sx[p][lane];
                float xb = e_b * inv * sx[p][64 + lane];
                float xa1 = __shfl_down(xa, 1), xb1 = __shfl_down(xb, 1);
                if (!(lane & 1)) {
                    sxw_p[lane >> 1]        = pack2(xa, xa1);
                    sxw_p[32 + (lane >> 1)] = pack2(xb, xb1);
                }
                if (lane == 0)
                    __hip_atomic_store(&flag_xw, t + 1, __ATOMIC_RELEASE,
                                       __HIP_MEMORY_SCOPE_WORKGROUP);
            } else if (a >= 64 && a < 192 && t + 1 < SS) {
                // waves 13-14: prefetch x_{t+1}
                const int idx = a - 64;
                sx[p ^ 1][idx] = xrow[(t + 1) * II + idx];
            } else if (a >= 192 && t + 1 < SS) {
                // wave 15: prefetch gix_{t+1}
                const float* gr = grow0 + (size_t)(t + 1) * II;
                const int l = a - 192;
                sgix[p ^ 1][l]      = gr[l];
                sgix[p ^ 1][64 + l] = gr[64 + l];
            }
        }
        __syncthreads();                              // B1: gates done, x prefetched

        if (tid < HH) {
            const float r = fsig(sgi[tid] + sgh[tid]);
            const float z = fsig(sgi[tid + HH] + sgh[tid + HH]);
            const float n = ftanh(sgi[tid + 2 * HH] + r * sgh[tid + 2 * HH]);
            h_reg = (1.f - z) * n + z * h_reg;
            float hn2 = __shfl_down(h_reg, 1);
            if (!(tid & 1)) s_xh_p[64 + (tid >> 1)] = pack2(h_reg, hn2);
            float pd = wt_j * h_reg;
            for (int off = 32; off; off >>= 1) pd += __shfl_down(pd, off);
            if (lane == 0) swave[wv] = pd;
        }
        __syncthreads();                              // B2: h ready (loop barrier)

        if (tid < HH) {
            // redundant per-thread online softmax over time (fast paths)
            float dot = swave[0] + swave[1] + swave[2] + swave[3] + bt_r;
            float st = ftanh(dot);
            float mn = fmaxf(m_run, st);
            float aa = fexp(m_run - mn), ww = fexp(st - mn);
            l_run = l_run * aa + ww;
            m_run = mn;
            c_reg = c_reg * aa + ww * h_reg;
        }
    }

    __syncthreads();
    if (tid < HH) {
        float ctx = c_reg * frcp(l_run);
        float pd = wf_j * ctx;
        for (int off = 32; off; off >>= 1) pd += __shfl_down(pd, off);
        if (lane == 0) swave[wv] = pd;
    }
    __syncthreads();
    if (tid == 0) {
        float logit = swave[0] + swave[1] + swave[2] + swave[3] + h2f(wsb[OFF_BF]);
        out[b] = fsig(logit);
    }
}

// ============ single-row fallback (R4 structure, GIX=0 path) ============
template <int GIX>
__global__ __launch_bounds__(1024, 4) void da_rnn_kernel(
    const float* __restrict__ x, const ushort_t* __restrict__ wsb,
    const float* __restrict__ gix, float* __restrict__ out)
{
    const int b    = blockIdx.x;
    const int tid  = threadIdx.x;
    const int lane = tid & 63;
    const int wv   = tid >> 6;
    const bool is_gate = (tid < 3 * HH);

    __shared__ __align__(16) uint32 whh_lds[WHH_LC * 768 * 4];
    __shared__ __align__(16) uint32 s_xh_p[192];
    __shared__ __align__(16) uint32 sxw_p[64];
    __shared__ __align__(16) float  sred[256];
    __shared__ __align__(16) float  sgi[3 * HH];
    __shared__ __align__(16) float  sgh[3 * HH];
    __shared__ __align__(16) float  sx[2][II];
    __shared__ __align__(16) float  sgix[2][II];
    __shared__ float swave[4];
    __shared__ int   flag_red;
    __shared__ int   flag_xw;

    if (tid == 0) { flag_red = 0; flag_xw = 0; }
    if (tid < II) s_xh_p[64 + tid] = 0u;

    uint4 wreg[16];
    const int a   = tid - 3 * HH;
    const int row = a & 127;
    const int s   = a >> 7;
    const uint4* whh_base = (const uint4*)(wsb + OFF_WHH) + (size_t)wv * 32 * 64 + lane;
    const uint4* wa_st = nullptr;
    float bias_i = 0.f, bias_h = 0.f, ba_a = 0.f, ba_b = 0.f;

    if (is_gate) {
        const uint4* wih_g = (const uint4*)(wsb + OFF_WIH) + (size_t)wv * 16 * 64 + lane;
        #pragma unroll
        for (int c = 0; c < 16; ++c) wreg[c] = wih_g[c * 64];
        bias_i = h2f(wsb[OFF_BIH + tid]);
        bias_h = h2f(wsb[OFF_BHH + tid]);
        #pragma unroll
        for (int c = 0; c < WHH_LC; ++c)
            ((uint4*)whh_lds)[(wv * WHH_LC + c) * 64 + lane] = whh_base[c * 64];
    } else {
        if (GIX) {
            const uint4* wah_g = (const uint4*)(wsb + OFF_WAH);
            const size_t gbh = ((size_t)(row >> 6) * 32 + s * 16) * 64 + (row & 63);
            #pragma unroll
            for (int i = 0; i < 16; ++i) wreg[i] = wah_g[gbh + (size_t)i * 64];
        } else {
            const uint4* wa_g = (const uint4*)(wsb + OFF_WA);
            const size_t gbase = ((size_t)(row >> 6) * 48 + s * 24) * 64 + (row & 63);
            #pragma unroll
            for (int i = 0; i < 16; ++i) wreg[i] = wa_g[gbase + (size_t)i * 64];
            wa_st = wa_g + gbase + (size_t)16 * 64;
        }
        ba_a = h2f(wsb[OFF_BA + lane]);
        ba_b = h2f(wsb[OFF_BA + 64 + lane]);
    }

    float h_reg = 0.f, c_reg = 0.f, m_run = -2.0f, l_run = 0.f;
    float wt_j = 0.f, wf_j = 0.f, bt_r = 0.f;
    if (tid < HH) {
        wt_j = h2f(wsb[OFF_WT + tid]);
        wf_j = h2f(wsb[OFF_WF + tid]);
        bt_r = h2f(wsb[OFF_BT]);
    }

    const float* xrow  = x + (size_t)b * SS * II;
    const float* grow0 = GIX ? (gix + (size_t)b * SS * II) : nullptr;
    if (!is_gate && a >= 64 && a < 192) {
        const int idx = a - 64;
        float v = xrow[idx];
        sx[0][idx] = v;
        if (!GIX) {
            float vn = __shfl_down(v, 1);
            if (!(idx & 1)) s_xh_p[idx >> 1] = pack2(v, vn);
        }
    }
    if (GIX && !is_gate && a >= 192) {
        const int l = a - 192;
        sgix[0][l]      = grow0[l];
        sgix[0][64 + l] = grow0[64 + l];
    }
    __syncthreads();

    const uint4* st4 = (const uint4*)s_xh_p;
    const uint4* shp = (const uint4*)s_xh_p + 16;
    const uint4* xwp = (const uint4*)sxw_p;
    const uint4* whl = (const uint4*)whh_lds + (size_t)(wv * WHH_LC) * 64 + lane;

    for (int t = 0; t < SS; ++t) {
        const int p = t & 1;

        if (is_gate) {
            float gh = bias_h;
            #pragma unroll
            for (int c = 0; c < WHH_LC; ++c) gh = dot4(whl[c * 64], shp[c], gh);
            #pragma unroll 4
            for (int c = WHH_LC; c < 32; ++c) gh = dot4(whh_base[c * 64], shp[c], gh);
            sgh[tid] = gh;
            while (__hip_atomic_load(&flag_xw, __ATOMIC_ACQUIRE,
                                     __HIP_MEMORY_SCOPE_WORKGROUP) <= t) {}
            float gi = bias_i;
            #pragma unroll
            for (int c = 0; c < 16; ++c) gi = dot4(wreg[c], xwp[c], gi);
            sgi[tid] = gi;
        } else {
            float acc;
            if (GIX) {
                acc = 0.f;
                #pragma unroll
                for (int i = 0; i < 16; ++i) acc = dot4(wreg[i], shp[s * 16 + i], acc);
            } else {
                acc = 0.f;
                #pragma unroll
                for (int i = 0; i < 16; ++i) acc = dot4(wreg[i], st4[s * 24 + i], acc);
                #pragma unroll 4
                for (int i = 0; i < 8; ++i) acc = dot4(wa_st[i * 64], st4[s * 24 + 16 + i], acc);
            }
            sred[a] = acc;
            if (lane == 0)
                __hip_atomic_fetch_add(&flag_red, 1, __ATOMIC_ACQ_REL,
                                       __HIP_MEMORY_SCOPE_WORKGROUP);
            const int tgt = 4 * (t + 1);
            while (__hip_atomic_load(&flag_red, __ATOMIC_ACQUIRE,
                                     __HIP_MEMORY_SCOPE_WORKGROUP) < tgt) {}
            if (a < 64) {
                float s_a = sred[lane] + sred[128 + lane] + ba_a;
                float s_b = sred[64 + lane] + sred[192 + lane] + ba_b;
                if (GIX) { s_a += sgix[p][lane]; s_b += sgix[p][64 + lane]; }
                s_a = tanhf(s_a); s_b = tanhf(s_b);
                float m = fmaxf(s_a, s_b);
                for (int off = 32; off; off >>= 1) m = fmaxf(m, __shfl_xor(m, off));
                float e_a = expf(s_a - m), e_b = expf(s_b - m);
                float sum = e_a + e_b;
                for (int off = 32; off; off >>= 1) sum += __shfl_xor(sum, off);
                float inv = 1.f / sum;
                float xa = e_a * inv * sx[p][lane];
                float xb = e_b * inv * sx[p][64 + lane];
                float xa1 = __shfl_down(xa, 1), xb1 = __shfl_down(xb, 1);
                if (!(lane & 1)) {
                    sxw_p[lane >> 1]        = pack2(xa, xa1);
                    sxw_p[32 + (lane >> 1)] = pack2(xb, xb1);
                }
                if (lane == 0)
                    __hip_atomic_store(&flag_xw, t + 1, __ATOMIC_RELEASE,
                                       __HIP_MEMORY_SCOPE_WORKGROUP);
            } else if (a >= 64 && a < 192 && t + 1 < SS) {
                const int idx = a - 64;
                float v = xrow[(t + 1) * II + idx];
                sx[p ^ 1][idx] = v;
                if (!GIX) {
                    float vn = __shfl_down(v, 1);
                    if (!(idx & 1)) s_xh_p[idx >> 1] = pack2(v, vn);
                }
            } else if (GIX && a >= 192 && t + 1 < SS) {
                const float* gr = grow0 + (size_t)(t + 1) * II;
                const int l = a - 192;
                sgix[p ^ 1][l]      = gr[l];
                sgix[p ^ 1][64 + l] = gr[64 + l];
            }
        }
        __syncthreads();

        if (tid < HH) {
            const float r = 1.f / (1.f + expf(-(sgi[tid] + sgh[tid])));
            const float z = 1.f / (1.f + expf(-(sgi[tid + HH] + sgh[tid + HH])));
            const float n = tanhf(sgi[tid + 2 * HH] + r * sgh[tid + 2 * HH]);
            h_reg = (1.f - z) * n + z * h_reg;
            float hn2 = __shfl_down(h_reg, 1);
            if (!(tid & 1)) s_xh_p[64 + (tid >> 1)] = pack2(h_reg, hn2);
            float pd = wt_j * h_reg;
            for (int off = 32; off; off >>= 1) pd += __shfl_down(pd, off);
            if (lane == 0) swave[wv] = pd;
        }
        __syncthreads();

        if (tid < HH) {
            float dot = swave[0] + swave[1] + swave[2] + swave[3] + bt_r;
            float st = tanhf(dot);
            float mn = fmaxf(m_run, st);
            float aa = expf(m_run - mn), ww = expf(st - mn);
            l_run = l_run * aa + ww;
            m_run = mn;
            c_reg = c_reg * aa + ww * h_reg;
        }
    }

    __syncthreads();
    if (tid < HH) {
        float ctx = c_reg / l_run;
        float pd = wf_j * ctx;
        for (int off = 32; off; off >>= 1) pd += __shfl_down(pd, off);
        if (lane == 0) swave[wv] = pd;
    }
    __syncthreads();
    if (tid == 0) {
        float logit = swave[0] + swave[1] + swave[2] + swave[3] + h2f(wsb[OFF_BF]);
        out[b] = 1.f / (1.f + expf(-logit));
    }
}

extern "C" void kernel_launch(void* const* d_in, const int* in_sizes, int n_in,
                              void* d_out, int out_size, void* d_ws, size_t ws_size,
                              hipStream_t stream) {
    ushort_t* wsb = (ushort_t*)d_ws;
    const size_t WS_NEED = (size_t)OFF_GIX * 2 + (size_t)BB * SS * II * 4;
    const bool use_gix = ws_size >= WS_NEED;

    cvt_swz<<<dim3((128 * 48 + 255) / 256), dim3(256), 0, stream>>>(
        (const float*)d_in[1], wsb + OFF_WA, 128, 48, 384, 0);       // W_a  [128,384]
    cvt_swz<<<dim3((768 * 16 + 255) / 256), dim3(256), 0, stream>>>(
        (const float*)d_in[3], wsb + OFF_WIH, 768, 16, 128, 0);      // W_ih [768,128]
    cvt_swz<<<dim3((768 * 32 + 255) / 256), dim3(256), 0, stream>>>(
        (const float*)d_in[5], wsb + OFF_WHH, 768, 32, 256, 0);      // W_hh [768,256]
    if (use_gix) {
        cvt_swz<<<dim3((128 * 32 + 255) / 256), dim3(256), 0, stream>>>(
            (const float*)d_in[1], wsb + OFF_WAH, 128, 32, 384, 128); // W_a h-part
        cvt_swz8<<<dim3((768 * RES8 + 255) / 256), dim3(256), 0, stream>>>(
            (const float*)d_in[5], wsb + OFF_WHH8, 768, RES8, 256, DIRF * 8); // Whh e5m2 ch8..31
    }

    struct { int src_idx; int off; int n; } cv[7] = {
        {2, OFF_BA,  II}, {4, OFF_BIH, 3 * HH}, {6, OFF_BHH, 3 * HH},
        {7, OFF_WT,  HH}, {8, OFF_BT, 1}, {9, OFF_WF, HH}, {10, OFF_BF, 1},
    };
    for (int i = 0; i < 7; ++i) {
        int blocks = (cv[i].n + 255) / 256;
        cvt_f32_f16<<<dim3(blocks), dim3(256), 0, stream>>>(
            (const float*)d_in[cv[i].src_idx], wsb + cv[i].off, cv[i].n);
    }

    float* gixf = (float*)(wsb + OFF_GIX);
    if (use_gix) {
        gix_kernel<<<dim3(BB), dim3(512), 0, stream>>>(
            (const float*)d_in[0], wsb, gixf);
        da_rnn_r13_kernel<<<dim3(BB), dim3(1024), 0, stream>>>(
            (const float*)d_in[0], wsb, gixf, (float*)d_out);
    } else {
        da_rnn_kernel<0><<<dim3(BB), dim3(1024), 0, stream>>>(
            (const float*)d_in[0], wsb, nullptr, (float*)d_out);
    }
}